// Round 1
// 439.362 us; speedup vs baseline: 1.1725x; 1.1725x over previous
//
#include <hip/hip_runtime.h>
#include <hip/hip_bf16.h>
#include <cstdint>

using bf16 = __hip_bfloat16;
typedef __attribute__((ext_vector_type(8))) short bf16x8;
typedef __attribute__((ext_vector_type(4))) float f32x4;

struct alignas(16) B8 { bf16 h[8]; };
struct alignas(8)  B4 { bf16 h[4]; };

__device__ __forceinline__ void gll16(const void* g, void* l) {
  __builtin_amdgcn_global_load_lds((__attribute__((address_space(1))) void*)g,
                                   (__attribute__((address_space(3))) void*)l,
                                   16, 0, 0);
}

// ---------------- cast fp32 -> bf16 (vectorized) ----------------
__global__ void cast_f32_bf16(const float* __restrict__ in, bf16* __restrict__ out, long long n) {
  long long i = ((long long)blockIdx.x * blockDim.x + threadIdx.x) * 8;
  if (i >= n) return;
  float4 v0 = *(const float4*)(in + i);
  float4 v1 = *(const float4*)(in + i + 4);
  B8 o;
  o.h[0] = __float2bfloat16(v0.x); o.h[1] = __float2bfloat16(v0.y);
  o.h[2] = __float2bfloat16(v0.z); o.h[3] = __float2bfloat16(v0.w);
  o.h[4] = __float2bfloat16(v1.x); o.h[5] = __float2bfloat16(v1.y);
  o.h[6] = __float2bfloat16(v1.z); o.h[7] = __float2bfloat16(v1.w);
  *(B8*)(out + i) = o;
}

// ---------------- transpose + cast: W[K][N] fp32 -> WT[N][K] bf16 ----------------
__global__ void tcast(const float* __restrict__ W, bf16* __restrict__ WT, int K, int N) {
  __shared__ float tile[32][33];
  int k0 = blockIdx.y * 32, n0 = blockIdx.x * 32;
  int tx = threadIdx.x, ty = threadIdx.y;  // block (32,8)
  for (int yy = ty; yy < 32; yy += 8)
    tile[yy][tx] = W[(size_t)(k0 + yy) * N + n0 + tx];
  __syncthreads();
  for (int yy = ty; yy < 32; yy += 8)
    WT[(size_t)(n0 + yy) * K + k0 + tx] = __float2bfloat16(tile[tx][yy]);
}

// =================================================================================
// Fused QKV GEMM:  T = x_bf @ [Wq | Wkv]  (M=32768, N=3072, K=1024)
// 256x256 tile, BK=64, 512 threads (8 waves, 2Mx4N), 8-phase pipelined schedule:
//  - LDS = ring of 4 half-K slots per operand (256 rows x 32 k, 16KB each), 128KB.
//  - per phase: ds_read frag subtile + stage one half-slot (2x global_load_lds) ->
//    raw s_barrier -> lgkmcnt(0) -> setprio(1) -> 16 MFMA -> setprio(0) -> barrier.
//  - counted s_waitcnt vmcnt(4) twice per K-tile (4 loads always in flight); never
//    vmcnt(0) in the main loop (raw barriers, no compiler drain).
//  - chunk-XOR swizzle: physical 16B chunk = logical ^ ((row^(row>>2))&3).
//    Staging pre-swizzles the GLOBAL source address (LDS dest stays linear, as
//    global_load_lds requires); ds_read applies the same XOR -> 2-way conflicts.
// Epilogues:
//  - q tiles (bn<4): per-row softmax over the wave's 64-col head slice (* DH^-0.5).
//  - kv tiles: 2 heads/block. exp(k), v -> swizzled LDS [64][256] via b64 writes;
//    Z from registers (shfl reduce); R[d][e] partial via MFMA; fp32 atomics.
// =================================================================================
constexpr int QKV_NT = 12;   // N/256

__global__ __launch_bounds__(512, 2)
void gemm_qkv(const bf16* __restrict__ A, const bf16* __restrict__ BT,
              bf16* __restrict__ Yq, float* __restrict__ ctxAcc)
{
  __shared__ __align__(16) union {
    struct { bf16 a[4 * 8192]; bf16 b[4 * 8192]; } g;       // 4+4 slots (16KB each)
    struct { bf16 ekT[2][16384]; bf16 vT[2][16384]; } c;    // kv epilogue (swizzled [64][256])
  } sm;

  const int t = threadIdx.x;
  const int wave = t >> 6, lane = t & 63;
  const int lr = lane & 15, kq = lane >> 4;
  const int wm = wave >> 2, wn = wave & 3;
  const int bm = (int)blockIdx.x / QKV_NT, bn = (int)blockIdx.x % QKV_NT;
  const int m0 = bm * 256, n0 = bn * 256;

  // ---- staging constants: thread covers physical chunks t and t+512 of each half
  const int srow = t >> 2;                                   // 0..127
  const int cl = (t & 3) ^ ((srow ^ (srow >> 2)) & 3);       // logical k-chunk (same for both rows)
  const bf16* aop0 = A + (size_t)(m0 + srow) * 1024 + cl * 8;
  const bf16* aop1 = A + (size_t)(m0 + 128 + srow) * 1024 + cl * 8;
  const bf16* bop0 = BT + (size_t)(n0 + srow) * 1024 + cl * 8;
  const bf16* bop1 = BT + (size_t)(n0 + 128 + srow) * 1024 + cl * 8;
  bf16* const ldsA = sm.g.a;
  bf16* const ldsB = sm.g.b;
  const int wd0 = wave * 512;          // elems, wave-uniform dest (gll writes base+lane*16)
  const int wd1 = 4096 + wave * 512;

  // ---- fragment-read constants (swizzled chunk is a pure lane constant)
  const int fc = (kq ^ ((lr ^ (lr >> 2)) & 3)) * 8;          // elems
  const int arow = wm * 128 + lr;
  const int brow = wn * 64 + lr;

#define STAGE_A(slot, ko) do { gll16(aop0 + (ko), ldsA + (slot) * 8192 + wd0); \
                               gll16(aop1 + (ko), ldsA + (slot) * 8192 + wd1); } while (0)
#define STAGE_B(slot, ko) do { gll16(bop0 + (ko), ldsB + (slot) * 8192 + wd0); \
                               gll16(bop1 + (ko), ldsB + (slot) * 8192 + wd1); } while (0)
#define AFRAG(slot, i) (*(const bf16x8*)(ldsA + (slot) * 8192 + (arow + (i) * 16) * 32 + fc))
#define BFRAG(slot, j) (*(const bf16x8*)(ldsB + (slot) * 8192 + (brow + (j) * 16) * 32 + fc))

  const f32x4 zero = {0.f, 0.f, 0.f, 0.f};
  f32x4 acc[8][4];
  #pragma unroll
  for (int i = 0; i < 8; i++)
    #pragma unroll
    for (int j = 0; j < 4; j++) acc[i][j] = zero;

  // prologue: tile 0 -> slots {0,1}; wait kh0 pair, keep kh1 pair in flight
  STAGE_A(0, 0); STAGE_B(0, 0);
  STAGE_A(1, 32); STAGE_B(1, 32);
  asm volatile("s_waitcnt vmcnt(4)" ::: "memory");
  __builtin_amdgcn_s_barrier();
  __builtin_amdgcn_sched_barrier(0);

  #pragma unroll 2
  for (int kt = 0; kt < 16; ++kt) {
    const int s0 = (2 * kt) & 3, s1 = (2 * kt + 1) & 3;      // this tile's slots
    const int p0 = (2 * kt + 2) & 3, p1 = (2 * kt + 3) & 3;  // next tile's slots
    const int ko = (kt + 1) * 64;
    const bool more = kt < 15;
    bf16x8 a[4], b[4];

    // ---- phase 0: kh0 x C rows 0-63 ----
    #pragma unroll
    for (int j = 0; j < 4; j++) b[j] = BFRAG(s0, j);
    #pragma unroll
    for (int i = 0; i < 4; i++) a[i] = AFRAG(s0, i);
    if (more) STAGE_A(p0, ko);
    __builtin_amdgcn_s_barrier();
    asm volatile("s_waitcnt lgkmcnt(0)" ::: "memory");
    __builtin_amdgcn_sched_barrier(0);
    __builtin_amdgcn_s_setprio(1);
    #pragma unroll
    for (int i = 0; i < 4; i++)
      #pragma unroll
      for (int j = 0; j < 4; j++)
        acc[i][j] = __builtin_amdgcn_mfma_f32_16x16x32_bf16(a[i], b[j], acc[i][j], 0, 0, 0);
    __builtin_amdgcn_s_setprio(0);
    __builtin_amdgcn_s_barrier();

    // ---- phase 1: kh0 x C rows 64-127 ----
    #pragma unroll
    for (int i = 0; i < 4; i++) a[i] = AFRAG(s0, i + 4);
    if (more) STAGE_B(p0, ko);
    __builtin_amdgcn_s_barrier();
    asm volatile("s_waitcnt lgkmcnt(0)" ::: "memory");
    __builtin_amdgcn_sched_barrier(0);
    __builtin_amdgcn_s_setprio(1);
    #pragma unroll
    for (int i = 0; i < 4; i++)
      #pragma unroll
      for (int j = 0; j < 4; j++)
        acc[i + 4][j] = __builtin_amdgcn_mfma_f32_16x16x32_bf16(a[i], b[j], acc[i + 4][j], 0, 0, 0);
    __builtin_amdgcn_s_setprio(0);
    if (more) { asm volatile("s_waitcnt vmcnt(4)" ::: "memory"); }
    else      { asm volatile("s_waitcnt vmcnt(0)" ::: "memory"); }   // tail drain
    __builtin_amdgcn_s_barrier();
    __builtin_amdgcn_sched_barrier(0);

    // ---- phase 2: kh1 x C rows 0-63 ----
    #pragma unroll
    for (int j = 0; j < 4; j++) b[j] = BFRAG(s1, j);
    #pragma unroll
    for (int i = 0; i < 4; i++) a[i] = AFRAG(s1, i);
    if (more) STAGE_A(p1, ko + 32);
    __builtin_amdgcn_s_barrier();
    asm volatile("s_waitcnt lgkmcnt(0)" ::: "memory");
    __builtin_amdgcn_sched_barrier(0);
    __builtin_amdgcn_s_setprio(1);
    #pragma unroll
    for (int i = 0; i < 4; i++)
      #pragma unroll
      for (int j = 0; j < 4; j++)
        acc[i][j] = __builtin_amdgcn_mfma_f32_16x16x32_bf16(a[i], b[j], acc[i][j], 0, 0, 0);
    __builtin_amdgcn_s_setprio(0);
    __builtin_amdgcn_s_barrier();

    // ---- phase 3: kh1 x C rows 64-127 ----
    #pragma unroll
    for (int i = 0; i < 4; i++) a[i] = AFRAG(s1, i + 4);
    if (more) STAGE_B(p1, ko + 32);
    __builtin_amdgcn_s_barrier();
    asm volatile("s_waitcnt lgkmcnt(0)" ::: "memory");
    __builtin_amdgcn_sched_barrier(0);
    __builtin_amdgcn_s_setprio(1);
    #pragma unroll
    for (int i = 0; i < 4; i++)
      #pragma unroll
      for (int j = 0; j < 4; j++)
        acc[i + 4][j] = __builtin_amdgcn_mfma_f32_16x16x32_bf16(a[i], b[j], acc[i + 4][j], 0, 0, 0);
    __builtin_amdgcn_s_setprio(0);
    if (more) { asm volatile("s_waitcnt vmcnt(4)" ::: "memory"); }
    else      { asm volatile("s_waitcnt vmcnt(0)" ::: "memory"); }
    __builtin_amdgcn_s_barrier();
    __builtin_amdgcn_sched_barrier(0);
  }

  if (bn < 4) {
    // ---- fused q softmax: each wave's 64 cols = one head ----
    #pragma unroll
    for (int i = 0; i < 8; i++) {
      #pragma unroll
      for (int r = 0; r < 4; r++) {
        float m = fmaxf(fmaxf(acc[i][0][r], acc[i][1][r]),
                        fmaxf(acc[i][2][r], acc[i][3][r]));
        m = fmaxf(m, __shfl_xor(m, 1));
        m = fmaxf(m, __shfl_xor(m, 2));
        m = fmaxf(m, __shfl_xor(m, 4));
        m = fmaxf(m, __shfl_xor(m, 8));
        float ex[4]; float s = 0.f;
        #pragma unroll
        for (int j = 0; j < 4; j++) { ex[j] = __expf(acc[i][j][r] - m); s += ex[j]; }
        s += __shfl_xor(s, 1);
        s += __shfl_xor(s, 2);
        s += __shfl_xor(s, 4);
        s += __shfl_xor(s, 8);
        const float inv = 0.125f / s;           // scale = DH^-0.5
        const int row = m0 + wm * 128 + i * 16 + kq * 4 + r;
        bf16* yrow = Yq + (size_t)row * 1024 + n0 + wn * 64;
        #pragma unroll
        for (int j = 0; j < 4; j++)
          yrow[j * 16 + lr] = __float2bfloat16(ex[j] * inv);
      }
    }
  } else {
    // ---- fused context: tile = 256 s-rows x 2 heads (each head: 64 k | 64 v) ----
    const int bb = m0 >> 12;                  // batch (4096 rows per batch)
    const int h0 = (n0 - 1024) >> 7;          // first head of this tile
    const int hloc = wn >> 1, isV = wn & 1;   // wave role
    bf16* const dstT = (isV ? sm.c.vT[hloc] : sm.c.ekT[hloc]);

    float zp[4] = {0.f, 0.f, 0.f, 0.f};
    #pragma unroll
    for (int i = 0; i < 8; i++) {
      const int sbase = wm * 128 + i * 16 + kq * 4;
      const int sxo = sbase >> 3;             // chunk (constant across r)
      const int sby = (sbase & 7) * 2;        // byte offset within chunk (0 or 8)
      #pragma unroll
      for (int j = 0; j < 4; j++) {
        const int d = j * 16 + lr;
        B4 pk;
        if (!isV) {
          #pragma unroll
          for (int r = 0; r < 4; r++) {
            float e = __expf(acc[i][j][r]);
            zp[j] += e;
            pk.h[r] = __float2bfloat16(e);
          }
        } else {
          #pragma unroll
          for (int r = 0; r < 4; r++) pk.h[r] = __float2bfloat16(acc[i][j][r]);
        }
        *(B4*)((char*)dstT + d * 512 + ((sxo ^ (d & 7)) << 4) + sby) = pk;
      }
    }

    if (!isV) {
      // Z[d] partial over this wave's 128 s-rows, straight from registers
      #pragma unroll
      for (int j = 0; j < 4; j++) {
        zp[j] += __shfl_xor(zp[j], 16);
        zp[j] += __shfl_xor(zp[j], 32);
      }
      if (kq == 0) {
        float* zb = ctxAcc + (size_t)(bb * 16 + h0 + hloc) * 4160 + 4096;
        #pragma unroll
        for (int j = 0; j < 4; j++) atomicAdd(zb + j * 16 + lr, zp[j]);
      }
    }
    __syncthreads();

    // R[d][e] partial via MFMA over K=256 s-rows; wave -> (head = wave>>2, d-quad = wave&3)
    const int hh = wave >> 2, dq = wave & 3;
    const bf16* const ek = sm.c.ekT[hh];
    const bf16* const vv = sm.c.vT[hh];
    f32x4 racc[4] = {zero, zero, zero, zero};
    #pragma unroll
    for (int ks = 0; ks < 8; ks++) {
      const int ch = ks * 4 + kq;
      bf16x8 af = *(const bf16x8*)((const char*)ek + (dq * 16 + lr) * 512 + ((ch ^ (lr & 7)) << 4));
      #pragma unroll
      for (int j = 0; j < 4; j++) {
        bf16x8 bfr = *(const bf16x8*)((const char*)vv + (j * 16 + lr) * 512 + ((ch ^ (lr & 7)) << 4));
        racc[j] = __builtin_amdgcn_mfma_f32_16x16x32_bf16(af, bfr, racc[j], 0, 0, 0);
      }
    }
    float* cb = ctxAcc + (size_t)(bb * 16 + h0 + hh) * 4160;
    #pragma unroll
    for (int j = 0; j < 4; j++) {
      #pragma unroll
      for (int r = 0; r < 4; r++)
        atomicAdd(cb + (dq * 16 + kq * 4 + r) * 64 + j * 16 + lr, racc[j][r]);
    }
  }
#undef STAGE_A
#undef STAGE_B
#undef AFRAG
#undef BFRAG
}

// ---------------- ctxN[bh][d][e] = bf16( R[d][e] / Z[d] ) ----------------
__global__ __launch_bounds__(256) void ctx_finish(const float* __restrict__ ctxAcc,
                                                  bf16* __restrict__ ctxN) {
  const int bh = blockIdx.x;
  const int t = threadIdx.x;
  __shared__ float zs[64];
  const float* src = ctxAcc + (size_t)bh * 4160;
  if (t < 64) zs[t] = src[4096 + t];
  __syncthreads();
  for (int idx = t; idx < 4096; idx += 256)
    ctxN[(size_t)bh * 4096 + idx] = __float2bfloat16(src[idx] / zs[idx >> 6]);
}

// ---------------- W2T[b][n][h*64+d] = sum_e ctxN[bh][d][e] * WlinT[n][h*64+e] ----
__global__ __launch_bounds__(256) void make_w2t(const bf16* __restrict__ ctxN,
                                                const bf16* __restrict__ WlinT,
                                                bf16* __restrict__ W2T) {
  const int nc = blockIdx.x;      // 0..15
  const int bh = blockIdx.y;      // 0..127
  const int b = bh >> 4, h = bh & 15;
  const int t = threadIdx.x, lane = t & 63, w = t >> 6;
  float creg[64];
  const bf16* crow = ctxN + (size_t)bh * 4096 + lane * 64;
  #pragma unroll
  for (int e8 = 0; e8 < 8; e8++) {
    B8 v = *(const B8*)(crow + e8 * 8);
    #pragma unroll
    for (int j = 0; j < 8; j++) creg[e8 * 8 + j] = __bfloat162float(v.h[j]);
  }
  for (int i = 0; i < 16; i++) {
    const int n = nc * 64 + w * 16 + i;
    const bf16* wrow = WlinT + (size_t)n * 1024 + h * 64;
    float acc = 0.f;
    #pragma unroll
    for (int e8 = 0; e8 < 8; e8++) {
      B8 v = *(const B8*)(wrow + e8 * 8);
      #pragma unroll
      for (int j = 0; j < 8; j++) acc += creg[e8 * 8 + j] * __bfloat162float(v.h[j]);
    }
    W2T[((size_t)b * 1024 + n) * 1024 + h * 64 + lane] = __float2bfloat16(acc);
  }
}

// ---------------- out[b] = Yq[b] @ W2T[b]^T + blin, fp32 output -------------------
// per batch: M=4096, N=1024, K=1024; grid (256, 8)
__global__ __launch_bounds__(256)
void gemm_out(const bf16* __restrict__ Aall, const bf16* __restrict__ BTall,
              float* __restrict__ Call, const float* __restrict__ bias)
{
  __shared__ __align__(16) bf16 As[128 * 32];
  __shared__ __align__(16) bf16 Bs[128 * 32];
  const int bz = blockIdx.y;
  const bf16* A  = Aall  + (size_t)bz * 4096 * 1024;
  const bf16* BT = BTall + (size_t)bz * 1024 * 1024;
  float* C       = Call  + (size_t)bz * 4096 * 1024;
  const int nt = 8;
  const int bm = (int)blockIdx.x / nt, bn = (int)blockIdx.x % nt;
  const int m0 = bm * 128, n0 = bn * 128;
  const int t = threadIdx.x;
  const int wave = t >> 6, lane = t & 63;
  const int lr = lane & 15, kq = lane >> 4, kb = kq * 8;
  const int wm = (wave >> 1) * 64, wn = (wave & 1) * 64;

  const int srow = t >> 2;
  const int scol = (t & 3) * 8;
  const bf16* a_src0 = A + (size_t)(m0 + srow) * 1024 + scol;
  const bf16* a_src1 = A + (size_t)(m0 + 64 + srow) * 1024 + scol;
  const bf16* b_src0 = BT + (size_t)(n0 + srow) * 1024 + scol;
  const bf16* b_src1 = BT + (size_t)(n0 + 64 + srow) * 1024 + scol;
  bf16* a_dst0 = As + wave * 512;
  bf16* a_dst1 = As + 2048 + wave * 512;
  bf16* b_dst0 = Bs + wave * 512;
  bf16* b_dst1 = Bs + 2048 + wave * 512;

  f32x4 zero = {0.f, 0.f, 0.f, 0.f};
  f32x4 acc[4][4];
  #pragma unroll
  for (int i = 0; i < 4; i++)
    #pragma unroll
    for (int j = 0; j < 4; j++) acc[i][j] = zero;

  for (int kt = 0; kt < 32; ++kt) {
    __syncthreads();
    gll16(a_src0, a_dst0); gll16(a_src1, a_dst1);
    gll16(b_src0, b_dst0); gll16(b_src1, b_dst1);
    a_src0 += 32; a_src1 += 32; b_src0 += 32; b_src1 += 32;
    __syncthreads();
    bf16x8 a[4], b[4];
    #pragma unroll
    for (int i = 0; i < 4; i++) a[i] = *(const bf16x8*)(As + (wm + i * 16 + lr) * 32 + kb);
    #pragma unroll
    for (int j = 0; j < 4; j++) b[j] = *(const bf16x8*)(Bs + (wn + j * 16 + lr) * 32 + kb);
    #pragma unroll
    for (int i = 0; i < 4; i++)
      #pragma unroll
      for (int j = 0; j < 4; j++)
        acc[i][j] = __builtin_amdgcn_mfma_f32_16x16x32_bf16(a[i], b[j], acc[i][j], 0, 0, 0);
  }

  #pragma unroll
  for (int i = 0; i < 4; i++) {
    const int row0 = m0 + wm + i * 16 + kq * 4;
    #pragma unroll
    for (int j = 0; j < 4; j++) {
      const int col = n0 + wn + j * 16 + lr;
      const float bv = bias[col];
      #pragma unroll
      for (int r = 0; r < 4; r++)
        C[(size_t)(row0 + r) * 1024 + col] = acc[i][j][r] + bv;
    }
  }
}

// ---------------------------------------------------------------------------------
extern "C" void kernel_launch(void* const* d_in, const int* in_sizes, int n_in,
                              void* d_out, int out_size, void* d_ws, size_t ws_size,
                              hipStream_t stream) {
  (void)in_sizes; (void)n_in; (void)out_size; (void)ws_size;
  const float* x    = (const float*)d_in[0];
  const float* Wq   = (const float*)d_in[1];
  const float* Wkv  = (const float*)d_in[2];
  const float* Wlin = (const float*)d_in[3];
  const float* blin = (const float*)d_in[4];
  float* out = (float*)d_out;              // reference output dtype = float32

  // workspace layout (~155 MB total)
  bf16* x_bf  = (bf16*)d_ws;                  // 33,554,432
  bf16* WTc   = x_bf + 33554432;              // 3,145,728   [Wq^T | Wkv^T]
  bf16* WlinT = WTc + 3145728;                // 1,048,576
  bf16* Yq    = WlinT + 1048576;              // 33,554,432  (q only)
  bf16* ctxN  = Yq + 33554432;                // 524,288
  bf16* W2T   = ctxN + 524288;                // 8,388,608
  float* ctxAcc = (float*)(W2T + 8388608);    // 128 * 4160 fp32 (R | Z)

  cast_f32_bf16<<<16384, 256, 0, stream>>>(x, x_bf, 33554432LL);
  tcast<<<dim3(32, 32), dim3(32, 8), 0, stream>>>(Wq, WTc, 1024, 1024);
  tcast<<<dim3(64, 32), dim3(32, 8), 0, stream>>>(Wkv, WTc + 1048576, 1024, 2048);
  tcast<<<dim3(32, 32), dim3(32, 8), 0, stream>>>(Wlin, WlinT, 1024, 1024);

  hipMemsetAsync(ctxAcc, 0, (size_t)128 * 4160 * sizeof(float), stream);

  gemm_qkv<<<dim3(128 * QKV_NT), 512, 0, stream>>>(x_bf, WTc, Yq, ctxAcc);
  ctx_finish<<<128, 256, 0, stream>>>(ctxAcc, ctxN);
  make_w2t<<<dim3(16, 128), 256, 0, stream>>>(ctxN, WlinT, W2T);
  gemm_out<<<dim3(256, 8), 256, 0, stream>>>(Yq, W2T, out, blin);
}

// Round 2
// 418.662 us; speedup vs baseline: 1.2305x; 1.0494x over previous
//
#include <hip/hip_runtime.h>
#include <hip/hip_bf16.h>
#include <cstdint>

using bf16 = __hip_bfloat16;
typedef __attribute__((ext_vector_type(8))) short bf16x8;
typedef __attribute__((ext_vector_type(4))) float f32x4;

struct alignas(16) B8 { bf16 h[8]; };
struct alignas(8)  B4 { bf16 h[4]; };

__device__ __forceinline__ void gll16(const void* g, void* l) {
  __builtin_amdgcn_global_load_lds((__attribute__((address_space(1))) void*)g,
                                   (__attribute__((address_space(3))) void*)l,
                                   16, 0, 0);
}

// ---------------- cast fp32 -> bf16 (vectorized) ----------------
__global__ void cast_f32_bf16(const float* __restrict__ in, bf16* __restrict__ out, long long n) {
  long long i = ((long long)blockIdx.x * blockDim.x + threadIdx.x) * 8;
  if (i >= n) return;
  float4 v0 = *(const float4*)(in + i);
  float4 v1 = *(const float4*)(in + i + 4);
  B8 o;
  o.h[0] = __float2bfloat16(v0.x); o.h[1] = __float2bfloat16(v0.y);
  o.h[2] = __float2bfloat16(v0.z); o.h[3] = __float2bfloat16(v0.w);
  o.h[4] = __float2bfloat16(v1.x); o.h[5] = __float2bfloat16(v1.y);
  o.h[6] = __float2bfloat16(v1.z); o.h[7] = __float2bfloat16(v1.w);
  *(B8*)(out + i) = o;
}

// ---------------- transpose + cast: W[K][N] fp32 -> WT[N][K] bf16 ----------------
__global__ void tcast(const float* __restrict__ W, bf16* __restrict__ WT, int K, int N) {
  __shared__ float tile[32][33];
  int k0 = blockIdx.y * 32, n0 = blockIdx.x * 32;
  int tx = threadIdx.x, ty = threadIdx.y;  // block (32,8)
  for (int yy = ty; yy < 32; yy += 8)
    tile[yy][tx] = W[(size_t)(k0 + yy) * N + n0 + tx];
  __syncthreads();
  for (int yy = ty; yy < 32; yy += 8)
    WT[(size_t)(n0 + yy) * K + k0 + tx] = __float2bfloat16(tile[tx][yy]);
}

// =================================================================================
// Shared 256x256-tile, BK=64, 8-wave, 8-phase pipelined main loop (K=1024 fixed).
//  - LDS ring of 4 half-K slots per operand (256 rows x 32 k, 16KB each), 128KB.
//  - per phase: ds_read frag subtile + stage one half-slot (2x global_load_lds) ->
//    raw s_barrier -> lgkmcnt(0) -> setprio(1) -> 16 MFMA -> setprio(0) -> barrier.
//  - counted s_waitcnt vmcnt(4) twice per K-tile; never vmcnt(0) in the main loop.
//  - chunk-XOR swizzle: physical 16B chunk = logical ^ ((row^(row>>2))&3), applied
//    by pre-swizzling the GLOBAL source address (LDS dest linear, as
//    global_load_lds requires) and the matching XOR on ds_read addresses.
// =================================================================================
__device__ __forceinline__ void gemm_mainloop_256(
    const bf16* __restrict__ aop0, const bf16* __restrict__ aop1,
    const bf16* __restrict__ bop0, const bf16* __restrict__ bop1,
    bf16* ldsA, bf16* ldsB, int wd0, int wd1,
    int arow, int brow, int fc, f32x4 (&acc)[8][4])
{
#define STAGE_A(slot, ko) do { gll16(aop0 + (ko), ldsA + (slot) * 8192 + wd0); \
                               gll16(aop1 + (ko), ldsA + (slot) * 8192 + wd1); } while (0)
#define STAGE_B(slot, ko) do { gll16(bop0 + (ko), ldsB + (slot) * 8192 + wd0); \
                               gll16(bop1 + (ko), ldsB + (slot) * 8192 + wd1); } while (0)
#define AFRAG(slot, i) (*(const bf16x8*)(ldsA + (slot) * 8192 + (arow + (i) * 16) * 32 + fc))
#define BFRAG(slot, j) (*(const bf16x8*)(ldsB + (slot) * 8192 + (brow + (j) * 16) * 32 + fc))

  // prologue: tile 0 -> slots {0,1}; wait kh0 pair, keep kh1 pair in flight
  STAGE_A(0, 0); STAGE_B(0, 0);
  STAGE_A(1, 32); STAGE_B(1, 32);
  asm volatile("s_waitcnt vmcnt(4)" ::: "memory");
  __builtin_amdgcn_s_barrier();
  __builtin_amdgcn_sched_barrier(0);

  #pragma unroll 2
  for (int kt = 0; kt < 16; ++kt) {
    const int s0 = (2 * kt) & 3, s1 = (2 * kt + 1) & 3;      // this tile's slots
    const int p0 = (2 * kt + 2) & 3, p1 = (2 * kt + 3) & 3;  // next tile's slots
    const int ko = (kt + 1) * 64;
    const bool more = kt < 15;
    bf16x8 a[4], b[4];

    // ---- phase 0: kh0 x C rows 0-63 ----
    #pragma unroll
    for (int j = 0; j < 4; j++) b[j] = BFRAG(s0, j);
    #pragma unroll
    for (int i = 0; i < 4; i++) a[i] = AFRAG(s0, i);
    if (more) STAGE_A(p0, ko);
    __builtin_amdgcn_s_barrier();
    asm volatile("s_waitcnt lgkmcnt(0)" ::: "memory");
    __builtin_amdgcn_sched_barrier(0);
    __builtin_amdgcn_s_setprio(1);
    #pragma unroll
    for (int i = 0; i < 4; i++)
      #pragma unroll
      for (int j = 0; j < 4; j++)
        acc[i][j] = __builtin_amdgcn_mfma_f32_16x16x32_bf16(a[i], b[j], acc[i][j], 0, 0, 0);
    __builtin_amdgcn_s_setprio(0);
    __builtin_amdgcn_s_barrier();

    // ---- phase 1: kh0 x C rows 64-127 ----
    #pragma unroll
    for (int i = 0; i < 4; i++) a[i] = AFRAG(s0, i + 4);
    if (more) STAGE_B(p0, ko);
    __builtin_amdgcn_s_barrier();
    asm volatile("s_waitcnt lgkmcnt(0)" ::: "memory");
    __builtin_amdgcn_sched_barrier(0);
    __builtin_amdgcn_s_setprio(1);
    #pragma unroll
    for (int i = 0; i < 4; i++)
      #pragma unroll
      for (int j = 0; j < 4; j++)
        acc[i + 4][j] = __builtin_amdgcn_mfma_f32_16x16x32_bf16(a[i], b[j], acc[i + 4][j], 0, 0, 0);
    __builtin_amdgcn_s_setprio(0);
    if (more) { asm volatile("s_waitcnt vmcnt(4)" ::: "memory"); }
    else      { asm volatile("s_waitcnt vmcnt(0)" ::: "memory"); }   // tail drain
    __builtin_amdgcn_s_barrier();
    __builtin_amdgcn_sched_barrier(0);

    // ---- phase 2: kh1 x C rows 0-63 ----
    #pragma unroll
    for (int j = 0; j < 4; j++) b[j] = BFRAG(s1, j);
    #pragma unroll
    for (int i = 0; i < 4; i++) a[i] = AFRAG(s1, i);
    if (more) STAGE_A(p1, ko + 32);
    __builtin_amdgcn_s_barrier();
    asm volatile("s_waitcnt lgkmcnt(0)" ::: "memory");
    __builtin_amdgcn_sched_barrier(0);
    __builtin_amdgcn_s_setprio(1);
    #pragma unroll
    for (int i = 0; i < 4; i++)
      #pragma unroll
      for (int j = 0; j < 4; j++)
        acc[i][j] = __builtin_amdgcn_mfma_f32_16x16x32_bf16(a[i], b[j], acc[i][j], 0, 0, 0);
    __builtin_amdgcn_s_setprio(0);
    __builtin_amdgcn_s_barrier();

    // ---- phase 3: kh1 x C rows 64-127 ----
    #pragma unroll
    for (int i = 0; i < 4; i++) a[i] = AFRAG(s1, i + 4);
    if (more) STAGE_B(p1, ko + 32);
    __builtin_amdgcn_s_barrier();
    asm volatile("s_waitcnt lgkmcnt(0)" ::: "memory");
    __builtin_amdgcn_sched_barrier(0);
    __builtin_amdgcn_s_setprio(1);
    #pragma unroll
    for (int i = 0; i < 4; i++)
      #pragma unroll
      for (int j = 0; j < 4; j++)
        acc[i + 4][j] = __builtin_amdgcn_mfma_f32_16x16x32_bf16(a[i], b[j], acc[i + 4][j], 0, 0, 0);
    __builtin_amdgcn_s_setprio(0);
    if (more) { asm volatile("s_waitcnt vmcnt(4)" ::: "memory"); }
    else      { asm volatile("s_waitcnt vmcnt(0)" ::: "memory"); }
    __builtin_amdgcn_s_barrier();
    __builtin_amdgcn_sched_barrier(0);
  }
#undef STAGE_A
#undef STAGE_B
#undef AFRAG
#undef BFRAG
}

// =================================================================================
// Fused QKV GEMM:  T = x_bf @ [Wq | Wkv]  (M=32768, N=3072, K=1024)
//  - q tiles (bn<4): per-row softmax over the wave's 64-col head slice (* DH^-0.5).
//  - kv tiles: 2 heads/block. exp(k), v -> swizzled LDS [64][256] via b64 writes;
//    Z from registers (shfl reduce); R[d][e] partial via MFMA; fp32 atomics.
// =================================================================================
constexpr int QKV_NT = 12;   // N/256

__global__ __launch_bounds__(512, 2)
void gemm_qkv(const bf16* __restrict__ A, const bf16* __restrict__ BT,
              bf16* __restrict__ Yq, float* __restrict__ ctxAcc)
{
  __shared__ __align__(16) union {
    struct { bf16 a[4 * 8192]; bf16 b[4 * 8192]; } g;       // 4+4 slots (16KB each)
    struct { bf16 ekT[2][16384]; bf16 vT[2][16384]; } c;    // kv epilogue (swizzled [64][256])
  } sm;

  const int t = threadIdx.x;
  const int wave = t >> 6, lane = t & 63;
  const int lr = lane & 15, kq = lane >> 4;
  const int wm = wave >> 2, wn = wave & 3;
  const int bm = (int)blockIdx.x / QKV_NT, bn = (int)blockIdx.x % QKV_NT;
  const int m0 = bm * 256, n0 = bn * 256;

  // ---- staging constants: thread covers physical chunks t and t+512 of each half
  const int srow = t >> 2;                                   // 0..127
  const int cl = (t & 3) ^ ((srow ^ (srow >> 2)) & 3);       // logical k-chunk
  const bf16* aop0 = A + (size_t)(m0 + srow) * 1024 + cl * 8;
  const bf16* aop1 = A + (size_t)(m0 + 128 + srow) * 1024 + cl * 8;
  const bf16* bop0 = BT + (size_t)(n0 + srow) * 1024 + cl * 8;
  const bf16* bop1 = BT + (size_t)(n0 + 128 + srow) * 1024 + cl * 8;
  const int wd0 = wave * 512;          // elems, wave-uniform dest (gll writes base+lane*16)
  const int wd1 = 4096 + wave * 512;

  // ---- fragment-read constants (swizzled chunk is a pure lane constant)
  const int fc = (kq ^ ((lr ^ (lr >> 2)) & 3)) * 8;          // elems
  const int arow = wm * 128 + lr;
  const int brow = wn * 64 + lr;

  const f32x4 zero = {0.f, 0.f, 0.f, 0.f};
  f32x4 acc[8][4];
  #pragma unroll
  for (int i = 0; i < 8; i++)
    #pragma unroll
    for (int j = 0; j < 4; j++) acc[i][j] = zero;

  gemm_mainloop_256(aop0, aop1, bop0, bop1, sm.g.a, sm.g.b, wd0, wd1,
                    arow, brow, fc, acc);

  if (bn < 4) {
    // ---- fused q softmax: each wave's 64 cols = one head ----
    #pragma unroll
    for (int i = 0; i < 8; i++) {
      #pragma unroll
      for (int r = 0; r < 4; r++) {
        float m = fmaxf(fmaxf(acc[i][0][r], acc[i][1][r]),
                        fmaxf(acc[i][2][r], acc[i][3][r]));
        m = fmaxf(m, __shfl_xor(m, 1));
        m = fmaxf(m, __shfl_xor(m, 2));
        m = fmaxf(m, __shfl_xor(m, 4));
        m = fmaxf(m, __shfl_xor(m, 8));
        float ex[4]; float s = 0.f;
        #pragma unroll
        for (int j = 0; j < 4; j++) { ex[j] = __expf(acc[i][j][r] - m); s += ex[j]; }
        s += __shfl_xor(s, 1);
        s += __shfl_xor(s, 2);
        s += __shfl_xor(s, 4);
        s += __shfl_xor(s, 8);
        const float inv = 0.125f / s;           // scale = DH^-0.5
        const int row = m0 + wm * 128 + i * 16 + kq * 4 + r;
        bf16* yrow = Yq + (size_t)row * 1024 + n0 + wn * 64;
        #pragma unroll
        for (int j = 0; j < 4; j++)
          yrow[j * 16 + lr] = __float2bfloat16(ex[j] * inv);
      }
    }
  } else {
    // ---- fused context: tile = 256 s-rows x 2 heads (each head: 64 k | 64 v) ----
    const int bb = m0 >> 12;                  // batch (4096 rows per batch)
    const int h0 = (n0 - 1024) >> 7;          // first head of this tile
    const int hloc = wn >> 1, isV = wn & 1;   // wave role
    bf16* const dstT = (isV ? sm.c.vT[hloc] : sm.c.ekT[hloc]);

    float zp[4] = {0.f, 0.f, 0.f, 0.f};
    #pragma unroll
    for (int i = 0; i < 8; i++) {
      const int sbase = wm * 128 + i * 16 + kq * 4;
      const int sxo = sbase >> 3;             // chunk (constant across r)
      const int sby = (sbase & 7) * 2;        // byte offset within chunk (0 or 8)
      #pragma unroll
      for (int j = 0; j < 4; j++) {
        const int d = j * 16 + lr;
        B4 pk;
        if (!isV) {
          #pragma unroll
          for (int r = 0; r < 4; r++) {
            float e = __expf(acc[i][j][r]);
            zp[j] += e;
            pk.h[r] = __float2bfloat16(e);
          }
        } else {
          #pragma unroll
          for (int r = 0; r < 4; r++) pk.h[r] = __float2bfloat16(acc[i][j][r]);
        }
        *(B4*)((char*)dstT + d * 512 + ((sxo ^ (d & 7)) << 4) + sby) = pk;
      }
    }

    if (!isV) {
      // Z[d] partial over this wave's 128 s-rows, straight from registers
      #pragma unroll
      for (int j = 0; j < 4; j++) {
        zp[j] += __shfl_xor(zp[j], 16);
        zp[j] += __shfl_xor(zp[j], 32);
      }
      if (kq == 0) {
        float* zb = ctxAcc + (size_t)(bb * 16 + h0 + hloc) * 4160 + 4096;
        #pragma unroll
        for (int j = 0; j < 4; j++) atomicAdd(zb + j * 16 + lr, zp[j]);
      }
    }
    __syncthreads();

    // R[d][e] partial via MFMA over K=256 s-rows; wave -> (head = wave>>2, d-quad = wave&3)
    const int hh = wave >> 2, dq = wave & 3;
    const bf16* const ek = sm.c.ekT[hh];
    const bf16* const vv = sm.c.vT[hh];
    f32x4 racc[4] = {zero, zero, zero, zero};
    #pragma unroll
    for (int ks = 0; ks < 8; ks++) {
      const int ch = ks * 4 + kq;
      bf16x8 af = *(const bf16x8*)((const char*)ek + (dq * 16 + lr) * 512 + ((ch ^ (lr & 7)) << 4));
      #pragma unroll
      for (int j = 0; j < 4; j++) {
        bf16x8 bfr = *(const bf16x8*)((const char*)vv + (j * 16 + lr) * 512 + ((ch ^ (lr & 7)) << 4));
        racc[j] = __builtin_amdgcn_mfma_f32_16x16x32_bf16(af, bfr, racc[j], 0, 0, 0);
      }
    }
    float* cb = ctxAcc + (size_t)(bb * 16 + h0 + hh) * 4160;
    #pragma unroll
    for (int j = 0; j < 4; j++) {
      #pragma unroll
      for (int r = 0; r < 4; r++)
        atomicAdd(cb + (dq * 16 + kq * 4 + r) * 64 + j * 16 + lr, racc[j][r]);
    }
  }
}

// ---------------- W2T[b][n][h*64+d] = sum_e (R[bh][d][e]/Z[bh][d]) * WlinT[n][h*64+e]
// (ctx normalization folded in; reads fp32 ctxAcc directly)
__global__ __launch_bounds__(256) void make_w2t(const float* __restrict__ ctxAcc,
                                                const bf16* __restrict__ WlinT,
                                                bf16* __restrict__ W2T) {
  const int nc = blockIdx.x;      // 0..15
  const int bh = blockIdx.y;      // 0..127
  const int b = bh >> 4, h = bh & 15;
  const int t = threadIdx.x, lane = t & 63, w = t >> 6;
  const float* src = ctxAcc + (size_t)bh * 4160;
  const float invz = 1.0f / src[4096 + lane];   // Z[d], d = lane
  float creg[64];
  const float* crow = src + lane * 64;
  #pragma unroll
  for (int e4 = 0; e4 < 16; e4++) {
    float4 v = *(const float4*)(crow + e4 * 4);
    creg[e4 * 4 + 0] = v.x * invz; creg[e4 * 4 + 1] = v.y * invz;
    creg[e4 * 4 + 2] = v.z * invz; creg[e4 * 4 + 3] = v.w * invz;
  }
  for (int i = 0; i < 16; i++) {
    const int n = nc * 64 + w * 16 + i;
    const bf16* wrow = WlinT + (size_t)n * 1024 + h * 64;
    float acc = 0.f;
    #pragma unroll
    for (int e8 = 0; e8 < 8; e8++) {
      B8 v = *(const B8*)(wrow + e8 * 8);
      #pragma unroll
      for (int j = 0; j < 8; j++) acc += creg[e8 * 8 + j] * __bfloat162float(v.h[j]);
    }
    W2T[((size_t)b * 1024 + n) * 1024 + h * 64 + lane] = __float2bfloat16(acc);
  }
}

// ---------------- out[b] = Yq[b] @ W2T[b]^T + blin, fp32 output -------------------
// per batch: M=4096, N=1024, K=1024; 256x256 tiles, 8-phase pipeline; grid (64, 8)
__global__ __launch_bounds__(512, 2)
void gemm_out(const bf16* __restrict__ Aall, const bf16* __restrict__ BTall,
              float* __restrict__ Call, const float* __restrict__ bias)
{
  __shared__ __align__(16) struct { bf16 a[4 * 8192]; bf16 b[4 * 8192]; } sm;
  const int t = threadIdx.x;
  const int wave = t >> 6, lane = t & 63;
  const int lr = lane & 15, kq = lane >> 4;
  const int wm = wave >> 2, wn = wave & 3;
  const int bz = blockIdx.y;
  const int bm = (int)blockIdx.x >> 2, bn = (int)blockIdx.x & 3;
  const int m0 = bm * 256, n0 = bn * 256;
  const bf16* A  = Aall  + (size_t)bz * 4096 * 1024;
  const bf16* BT = BTall + (size_t)bz * 1024 * 1024;
  float* C       = Call  + (size_t)bz * 4096 * 1024;

  const int srow = t >> 2;
  const int cl = (t & 3) ^ ((srow ^ (srow >> 2)) & 3);
  const bf16* aop0 = A + (size_t)(m0 + srow) * 1024 + cl * 8;
  const bf16* aop1 = A + (size_t)(m0 + 128 + srow) * 1024 + cl * 8;
  const bf16* bop0 = BT + (size_t)(n0 + srow) * 1024 + cl * 8;
  const bf16* bop1 = BT + (size_t)(n0 + 128 + srow) * 1024 + cl * 8;
  const int wd0 = wave * 512;
  const int wd1 = 4096 + wave * 512;

  const int fc = (kq ^ ((lr ^ (lr >> 2)) & 3)) * 8;
  const int arow = wm * 128 + lr;
  const int brow = wn * 64 + lr;

  const f32x4 zero = {0.f, 0.f, 0.f, 0.f};
  f32x4 acc[8][4];
  #pragma unroll
  for (int i = 0; i < 8; i++)
    #pragma unroll
    for (int j = 0; j < 4; j++) acc[i][j] = zero;

  gemm_mainloop_256(aop0, aop1, bop0, bop1, sm.a, sm.b, wd0, wd1,
                    arow, brow, fc, acc);

  float bv[4];
  #pragma unroll
  for (int j = 0; j < 4; j++) bv[j] = bias[n0 + wn * 64 + j * 16 + lr];
  #pragma unroll
  for (int i = 0; i < 8; i++) {
    const int row0 = m0 + wm * 128 + i * 16 + kq * 4;
    #pragma unroll
    for (int j = 0; j < 4; j++) {
      const int col = n0 + wn * 64 + j * 16 + lr;
      #pragma unroll
      for (int r = 0; r < 4; r++)
        C[(size_t)(row0 + r) * 1024 + col] = acc[i][j][r] + bv[j];
    }
  }
}

// ---------------------------------------------------------------------------------
extern "C" void kernel_launch(void* const* d_in, const int* in_sizes, int n_in,
                              void* d_out, int out_size, void* d_ws, size_t ws_size,
                              hipStream_t stream) {
  (void)in_sizes; (void)n_in; (void)out_size; (void)ws_size;
  const float* x    = (const float*)d_in[0];
  const float* Wq   = (const float*)d_in[1];
  const float* Wkv  = (const float*)d_in[2];
  const float* Wlin = (const float*)d_in[3];
  const float* blin = (const float*)d_in[4];
  float* out = (float*)d_out;              // reference output dtype = float32

  // workspace layout (~160 MB total)
  bf16* x_bf  = (bf16*)d_ws;                  // 33,554,432
  bf16* WTc   = x_bf + 33554432;              // 3,145,728   [Wq^T | Wkv^T]
  bf16* WlinT = WTc + 3145728;                // 1,048,576
  bf16* Yq    = WlinT + 1048576;              // 33,554,432  (q only)
  bf16* W2T   = Yq + 33554432;                // 8,388,608
  float* ctxAcc = (float*)(W2T + 8388608);    // 128 * 4160 fp32 (R | Z)

  cast_f32_bf16<<<16384, 256, 0, stream>>>(x, x_bf, 33554432LL);
  tcast<<<dim3(32, 32), dim3(32, 8), 0, stream>>>(Wq, WTc, 1024, 1024);
  tcast<<<dim3(64, 32), dim3(32, 8), 0, stream>>>(Wkv, WTc + 1048576, 1024, 2048);
  tcast<<<dim3(32, 32), dim3(32, 8), 0, stream>>>(Wlin, WlinT, 1024, 1024);

  hipMemsetAsync(ctxAcc, 0, (size_t)128 * 4160 * sizeof(float), stream);

  gemm_qkv<<<dim3(128 * QKV_NT), 512, 0, stream>>>(x_bf, WTc, Yq, ctxAcc);
  make_w2t<<<dim3(16, 128), 256, 0, stream>>>(ctxAcc, WlinT, W2T);
  gemm_out<<<dim3(64, 8), 512, 0, stream>>>(Yq, W2T, out, blin);
}

// Round 3
// 403.390 us; speedup vs baseline: 1.2771x; 1.0379x over previous
//
#include <hip/hip_runtime.h>
#include <hip/hip_bf16.h>
#include <cstdint>

using bf16 = __hip_bfloat16;
typedef __attribute__((ext_vector_type(8))) short bf16x8;
typedef __attribute__((ext_vector_type(4))) float f32x4;

struct alignas(16) B8 { bf16 h[8]; };
struct alignas(8)  B4 { bf16 h[4]; };

__device__ __forceinline__ void gll16(const void* g, void* l) {
  __builtin_amdgcn_global_load_lds((__attribute__((address_space(1))) void*)g,
                                   (__attribute__((address_space(3))) void*)l,
                                   16, 0, 0);
}

// ---------------- cast fp32 -> bf16 (vectorized) ----------------
__global__ void cast_f32_bf16(const float* __restrict__ in, bf16* __restrict__ out, long long n) {
  long long i = ((long long)blockIdx.x * blockDim.x + threadIdx.x) * 8;
  if (i >= n) return;
  float4 v0 = *(const float4*)(in + i);
  float4 v1 = *(const float4*)(in + i + 4);
  B8 o;
  o.h[0] = __float2bfloat16(v0.x); o.h[1] = __float2bfloat16(v0.y);
  o.h[2] = __float2bfloat16(v0.z); o.h[3] = __float2bfloat16(v0.w);
  o.h[4] = __float2bfloat16(v1.x); o.h[5] = __float2bfloat16(v1.y);
  o.h[6] = __float2bfloat16(v1.z); o.h[7] = __float2bfloat16(v1.w);
  *(B8*)(out + i) = o;
}

// ---------------- transpose + cast: W[K][N] fp32 -> WT[N][K] bf16 ----------------
__global__ void tcast(const float* __restrict__ W, bf16* __restrict__ WT, int K, int N) {
  __shared__ float tile[32][33];
  int k0 = blockIdx.y * 32, n0 = blockIdx.x * 32;
  int tx = threadIdx.x, ty = threadIdx.y;  // block (32,8)
  for (int yy = ty; yy < 32; yy += 8)
    tile[yy][tx] = W[(size_t)(k0 + yy) * N + n0 + tx];
  __syncthreads();
  for (int yy = ty; yy < 32; yy += 8)
    WT[(size_t)(n0 + yy) * K + k0 + tx] = __float2bfloat16(tile[tx][yy]);
}

// =================================================================================
// Shared 256x256-tile, BK=64, 8-wave, 8-phase pipelined main loop (K=1024 fixed).
//  - LDS ring of 4 half-K slots per operand (256 rows x 32 k, 16KB each), 128KB.
//  - per phase: ds_read frag subtile + stage one half-slot (2x global_load_lds) ->
//    raw s_barrier -> lgkmcnt(0) -> setprio(1) -> 16 MFMA -> setprio(0) -> barrier.
//  - counted s_waitcnt vmcnt(4) twice per K-tile; never vmcnt(0) in the main loop.
//  - chunk-XOR swizzle: physical 16B chunk = logical ^ ((row^(row>>2))&3), applied
//    by pre-swizzling the GLOBAL source address (LDS dest linear, as
//    global_load_lds requires) and the matching XOR on ds_read addresses.
// =================================================================================
__device__ __forceinline__ void gemm_mainloop_256(
    const bf16* __restrict__ aop0, const bf16* __restrict__ aop1,
    const bf16* __restrict__ bop0, const bf16* __restrict__ bop1,
    bf16* ldsA, bf16* ldsB, int wd0, int wd1,
    int arow, int brow, int fc, f32x4 (&acc)[8][4])
{
#define STAGE_A(slot, ko) do { gll16(aop0 + (ko), ldsA + (slot) * 8192 + wd0); \
                               gll16(aop1 + (ko), ldsA + (slot) * 8192 + wd1); } while (0)
#define STAGE_B(slot, ko) do { gll16(bop0 + (ko), ldsB + (slot) * 8192 + wd0); \
                               gll16(bop1 + (ko), ldsB + (slot) * 8192 + wd1); } while (0)
#define AFRAG(slot, i) (*(const bf16x8*)(ldsA + (slot) * 8192 + (arow + (i) * 16) * 32 + fc))
#define BFRAG(slot, j) (*(const bf16x8*)(ldsB + (slot) * 8192 + (brow + (j) * 16) * 32 + fc))

  // prologue: tile 0 -> slots {0,1}; wait kh0 pair, keep kh1 pair in flight
  STAGE_A(0, 0); STAGE_B(0, 0);
  STAGE_A(1, 32); STAGE_B(1, 32);
  asm volatile("s_waitcnt vmcnt(4)" ::: "memory");
  __builtin_amdgcn_s_barrier();
  __builtin_amdgcn_sched_barrier(0);

  #pragma unroll 2
  for (int kt = 0; kt < 16; ++kt) {
    const int s0 = (2 * kt) & 3, s1 = (2 * kt + 1) & 3;      // this tile's slots
    const int p0 = (2 * kt + 2) & 3, p1 = (2 * kt + 3) & 3;  // next tile's slots
    const int ko = (kt + 1) * 64;
    const bool more = kt < 15;
    bf16x8 a[4], b[4];

    // ---- phase 0: kh0 x C rows 0-63 ----
    #pragma unroll
    for (int j = 0; j < 4; j++) b[j] = BFRAG(s0, j);
    #pragma unroll
    for (int i = 0; i < 4; i++) a[i] = AFRAG(s0, i);
    if (more) STAGE_A(p0, ko);
    __builtin_amdgcn_s_barrier();
    asm volatile("s_waitcnt lgkmcnt(0)" ::: "memory");
    __builtin_amdgcn_sched_barrier(0);
    __builtin_amdgcn_s_setprio(1);
    #pragma unroll
    for (int i = 0; i < 4; i++)
      #pragma unroll
      for (int j = 0; j < 4; j++)
        acc[i][j] = __builtin_amdgcn_mfma_f32_16x16x32_bf16(a[i], b[j], acc[i][j], 0, 0, 0);
    __builtin_amdgcn_s_setprio(0);
    __builtin_amdgcn_s_barrier();

    // ---- phase 1: kh0 x C rows 64-127 ----
    #pragma unroll
    for (int i = 0; i < 4; i++) a[i] = AFRAG(s0, i + 4);
    if (more) STAGE_B(p0, ko);
    __builtin_amdgcn_s_barrier();
    asm volatile("s_waitcnt lgkmcnt(0)" ::: "memory");
    __builtin_amdgcn_sched_barrier(0);
    __builtin_amdgcn_s_setprio(1);
    #pragma unroll
    for (int i = 0; i < 4; i++)
      #pragma unroll
      for (int j = 0; j < 4; j++)
        acc[i + 4][j] = __builtin_amdgcn_mfma_f32_16x16x32_bf16(a[i], b[j], acc[i + 4][j], 0, 0, 0);
    __builtin_amdgcn_s_setprio(0);
    if (more) { asm volatile("s_waitcnt vmcnt(4)" ::: "memory"); }
    else      { asm volatile("s_waitcnt vmcnt(0)" ::: "memory"); }   // tail drain
    __builtin_amdgcn_s_barrier();
    __builtin_amdgcn_sched_barrier(0);

    // ---- phase 2: kh1 x C rows 0-63 ----
    #pragma unroll
    for (int j = 0; j < 4; j++) b[j] = BFRAG(s1, j);
    #pragma unroll
    for (int i = 0; i < 4; i++) a[i] = AFRAG(s1, i);
    if (more) STAGE_A(p1, ko + 32);
    __builtin_amdgcn_s_barrier();
    asm volatile("s_waitcnt lgkmcnt(0)" ::: "memory");
    __builtin_amdgcn_sched_barrier(0);
    __builtin_amdgcn_s_setprio(1);
    #pragma unroll
    for (int i = 0; i < 4; i++)
      #pragma unroll
      for (int j = 0; j < 4; j++)
        acc[i][j] = __builtin_amdgcn_mfma_f32_16x16x32_bf16(a[i], b[j], acc[i][j], 0, 0, 0);
    __builtin_amdgcn_s_setprio(0);
    __builtin_amdgcn_s_barrier();

    // ---- phase 3: kh1 x C rows 64-127 ----
    #pragma unroll
    for (int i = 0; i < 4; i++) a[i] = AFRAG(s1, i + 4);
    if (more) STAGE_B(p1, ko + 32);
    __builtin_amdgcn_s_barrier();
    asm volatile("s_waitcnt lgkmcnt(0)" ::: "memory");
    __builtin_amdgcn_sched_barrier(0);
    __builtin_amdgcn_s_setprio(1);
    #pragma unroll
    for (int i = 0; i < 4; i++)
      #pragma unroll
      for (int j = 0; j < 4; j++)
        acc[i + 4][j] = __builtin_amdgcn_mfma_f32_16x16x32_bf16(a[i], b[j], acc[i + 4][j], 0, 0, 0);
    __builtin_amdgcn_s_setprio(0);
    if (more) { asm volatile("s_waitcnt vmcnt(4)" ::: "memory"); }
    else      { asm volatile("s_waitcnt vmcnt(0)" ::: "memory"); }
    __builtin_amdgcn_s_barrier();
    __builtin_amdgcn_sched_barrier(0);
  }
#undef STAGE_A
#undef STAGE_B
#undef AFRAG
#undef BFRAG
}

// =================================================================================
// Fused QKV GEMM:  T = x_bf @ [Wq | Wkv]  (M=32768, N=3072, K=1024)
//  - XCD-chunked block swizzle: 1536 blocks = 8 XCDs x 192. Each XCD owns a
//    contiguous bm-major range so all 12 bn-tiles sharing an A-panel run on one
//    XCD back-to-back (B panel 3MB + streaming A resident in that XCD's 4MB L2).
//  - q tiles (bn<4): per-row softmax over the wave's 64-col head slice (* DH^-0.5).
//  - kv tiles: 2 heads/block. exp(k), v -> swizzled LDS [64][256] via b64 writes;
//    Z from registers (shfl reduce); R[d][e] partial via MFMA; fp32 atomics.
// =================================================================================
constexpr int QKV_NT = 12;   // N/256

__global__ __launch_bounds__(512, 2)
void gemm_qkv(const bf16* __restrict__ A, const bf16* __restrict__ BT,
              bf16* __restrict__ Yq, float* __restrict__ ctxAcc)
{
  __shared__ __align__(16) union {
    struct { bf16 a[4 * 8192]; bf16 b[4 * 8192]; } g;       // 4+4 slots (16KB each)
    struct { bf16 ekT[2][16384]; bf16 vT[2][16384]; } c;    // kv epilogue (swizzled [64][256])
  } sm;

  const int t = threadIdx.x;
  const int wave = t >> 6, lane = t & 63;
  const int lr = lane & 15, kq = lane >> 4;
  const int wm = wave >> 2, wn = wave & 3;
  // XCD-chunked swizzle (bijective: 1536 = 8 * 192; dispatch round-robins bid%8)
  const int bid = (int)blockIdx.x;
  const int swz = (bid & 7) * 192 + (bid >> 3);
  const int bm = swz / QKV_NT, bn = swz % QKV_NT;
  const int m0 = bm * 256, n0 = bn * 256;

  // ---- staging constants: thread covers physical chunks t and t+512 of each half
  const int srow = t >> 2;                                   // 0..127
  const int cl = (t & 3) ^ ((srow ^ (srow >> 2)) & 3);       // logical k-chunk
  const bf16* aop0 = A + (size_t)(m0 + srow) * 1024 + cl * 8;
  const bf16* aop1 = A + (size_t)(m0 + 128 + srow) * 1024 + cl * 8;
  const bf16* bop0 = BT + (size_t)(n0 + srow) * 1024 + cl * 8;
  const bf16* bop1 = BT + (size_t)(n0 + 128 + srow) * 1024 + cl * 8;
  const int wd0 = wave * 512;          // elems, wave-uniform dest (gll writes base+lane*16)
  const int wd1 = 4096 + wave * 512;

  // ---- fragment-read constants (swizzled chunk is a pure lane constant)
  const int fc = (kq ^ ((lr ^ (lr >> 2)) & 3)) * 8;          // elems
  const int arow = wm * 128 + lr;
  const int brow = wn * 64 + lr;

  const f32x4 zero = {0.f, 0.f, 0.f, 0.f};
  f32x4 acc[8][4];
  #pragma unroll
  for (int i = 0; i < 8; i++)
    #pragma unroll
    for (int j = 0; j < 4; j++) acc[i][j] = zero;

  gemm_mainloop_256(aop0, aop1, bop0, bop1, sm.g.a, sm.g.b, wd0, wd1,
                    arow, brow, fc, acc);

  if (bn < 4) {
    // ---- fused q softmax: each wave's 64 cols = one head ----
    #pragma unroll
    for (int i = 0; i < 8; i++) {
      #pragma unroll
      for (int r = 0; r < 4; r++) {
        float m = fmaxf(fmaxf(acc[i][0][r], acc[i][1][r]),
                        fmaxf(acc[i][2][r], acc[i][3][r]));
        m = fmaxf(m, __shfl_xor(m, 1));
        m = fmaxf(m, __shfl_xor(m, 2));
        m = fmaxf(m, __shfl_xor(m, 4));
        m = fmaxf(m, __shfl_xor(m, 8));
        float ex[4]; float s = 0.f;
        #pragma unroll
        for (int j = 0; j < 4; j++) { ex[j] = __expf(acc[i][j][r] - m); s += ex[j]; }
        s += __shfl_xor(s, 1);
        s += __shfl_xor(s, 2);
        s += __shfl_xor(s, 4);
        s += __shfl_xor(s, 8);
        const float inv = 0.125f / s;           // scale = DH^-0.5
        const int row = m0 + wm * 128 + i * 16 + kq * 4 + r;
        bf16* yrow = Yq + (size_t)row * 1024 + n0 + wn * 64;
        #pragma unroll
        for (int j = 0; j < 4; j++)
          yrow[j * 16 + lr] = __float2bfloat16(ex[j] * inv);
      }
    }
  } else {
    // ---- fused context: tile = 256 s-rows x 2 heads (each head: 64 k | 64 v) ----
    const int bb = m0 >> 12;                  // batch (4096 rows per batch)
    const int h0 = (n0 - 1024) >> 7;          // first head of this tile
    const int hloc = wn >> 1, isV = wn & 1;   // wave role
    bf16* const dstT = (isV ? sm.c.vT[hloc] : sm.c.ekT[hloc]);

    float zp[4] = {0.f, 0.f, 0.f, 0.f};
    #pragma unroll
    for (int i = 0; i < 8; i++) {
      const int sbase = wm * 128 + i * 16 + kq * 4;
      const int sxo = sbase >> 3;             // chunk (constant across r)
      const int sby = (sbase & 7) * 2;        // byte offset within chunk (0 or 8)
      #pragma unroll
      for (int j = 0; j < 4; j++) {
        const int d = j * 16 + lr;
        B4 pk;
        if (!isV) {
          #pragma unroll
          for (int r = 0; r < 4; r++) {
            float e = __expf(acc[i][j][r]);
            zp[j] += e;
            pk.h[r] = __float2bfloat16(e);
          }
        } else {
          #pragma unroll
          for (int r = 0; r < 4; r++) pk.h[r] = __float2bfloat16(acc[i][j][r]);
        }
        *(B4*)((char*)dstT + d * 512 + ((sxo ^ (d & 7)) << 4) + sby) = pk;
      }
    }

    if (!isV) {
      // Z[d] partial over this wave's 128 s-rows, straight from registers
      #pragma unroll
      for (int j = 0; j < 4; j++) {
        zp[j] += __shfl_xor(zp[j], 16);
        zp[j] += __shfl_xor(zp[j], 32);
      }
      if (kq == 0) {
        float* zb = ctxAcc + (size_t)(bb * 16 + h0 + hloc) * 4160 + 4096;
        #pragma unroll
        for (int j = 0; j < 4; j++) atomicAdd(zb + j * 16 + lr, zp[j]);
      }
    }
    __syncthreads();

    // R[d][e] partial via MFMA over K=256 s-rows; wave -> (head = wave>>2, d-quad = wave&3)
    const int hh = wave >> 2, dq = wave & 3;
    const bf16* const ek = sm.c.ekT[hh];
    const bf16* const vv = sm.c.vT[hh];
    f32x4 racc[4] = {zero, zero, zero, zero};
    #pragma unroll
    for (int ks = 0; ks < 8; ks++) {
      const int ch = ks * 4 + kq;
      bf16x8 af = *(const bf16x8*)((const char*)ek + (dq * 16 + lr) * 512 + ((ch ^ (lr & 7)) << 4));
      #pragma unroll
      for (int j = 0; j < 4; j++) {
        bf16x8 bfr = *(const bf16x8*)((const char*)vv + (j * 16 + lr) * 512 + ((ch ^ (lr & 7)) << 4));
        racc[j] = __builtin_amdgcn_mfma_f32_16x16x32_bf16(af, bfr, racc[j], 0, 0, 0);
      }
    }
    float* cb = ctxAcc + (size_t)(bb * 16 + h0 + hh) * 4160;
    #pragma unroll
    for (int j = 0; j < 4; j++) {
      #pragma unroll
      for (int r = 0; r < 4; r++)
        atomicAdd(cb + (dq * 16 + kq * 4 + r) * 64 + j * 16 + lr, racc[j][r]);
    }
  }
}

// ---------------- W2T[b][n][h*64+d] = sum_e (R[bh][d][e]/Z[bh][d]) * WlinT[n][h*64+e]
// (ctx normalization folded in; reads fp32 ctxAcc directly)
__global__ __launch_bounds__(256) void make_w2t(const float* __restrict__ ctxAcc,
                                                const bf16* __restrict__ WlinT,
                                                bf16* __restrict__ W2T) {
  const int nc = blockIdx.x;      // 0..15
  const int bh = blockIdx.y;      // 0..127
  const int b = bh >> 4, h = bh & 15;
  const int t = threadIdx.x, lane = t & 63, w = t >> 6;
  const float* src = ctxAcc + (size_t)bh * 4160;
  const float invz = 1.0f / src[4096 + lane];   // Z[d], d = lane
  float creg[64];
  const float* crow = src + lane * 64;
  #pragma unroll
  for (int e4 = 0; e4 < 16; e4++) {
    float4 v = *(const float4*)(crow + e4 * 4);
    creg[e4 * 4 + 0] = v.x * invz; creg[e4 * 4 + 1] = v.y * invz;
    creg[e4 * 4 + 2] = v.z * invz; creg[e4 * 4 + 3] = v.w * invz;
  }
  for (int i = 0; i < 16; i++) {
    const int n = nc * 64 + w * 16 + i;
    const bf16* wrow = WlinT + (size_t)n * 1024 + h * 64;
    float acc = 0.f;
    #pragma unroll
    for (int e8 = 0; e8 < 8; e8++) {
      B8 v = *(const B8*)(wrow + e8 * 8);
      #pragma unroll
      for (int j = 0; j < 8; j++) acc += creg[e8 * 8 + j] * __bfloat162float(v.h[j]);
    }
    W2T[((size_t)b * 1024 + n) * 1024 + h * 64 + lane] = __float2bfloat16(acc);
  }
}

// ---------------- out[b] = Yq[b] @ W2T[b]^T + blin, fp32 output -------------------
// per batch: M=4096, N=1024, K=1024; 256x256 tiles, 8-phase pipeline; grid 512
// XCD-chunked swizzle: each XCD owns one batch (64 blocks): W2T[b] (2MB) L2-resident.
__global__ __launch_bounds__(512, 2)
void gemm_out(const bf16* __restrict__ Aall, const bf16* __restrict__ BTall,
              float* __restrict__ Call, const float* __restrict__ bias)
{
  __shared__ __align__(16) struct { bf16 a[4 * 8192]; bf16 b[4 * 8192]; } sm;
  const int t = threadIdx.x;
  const int wave = t >> 6, lane = t & 63;
  const int lr = lane & 15, kq = lane >> 4;
  const int wm = wave >> 2, wn = wave & 3;
  // bijective XCD swizzle: 512 = 8 * 64; XCD x -> batch x
  const int bid = (int)blockIdx.x;
  const int swz = (bid & 7) * 64 + (bid >> 3);
  const int bz = swz >> 6;
  const int r  = swz & 63;
  const int bm = r >> 2, bn = r & 3;
  const int m0 = bm * 256, n0 = bn * 256;
  const bf16* A  = Aall  + (size_t)bz * 4096 * 1024;
  const bf16* BT = BTall + (size_t)bz * 1024 * 1024;
  float* C       = Call  + (size_t)bz * 4096 * 1024;

  const int srow = t >> 2;
  const int cl = (t & 3) ^ ((srow ^ (srow >> 2)) & 3);
  const bf16* aop0 = A + (size_t)(m0 + srow) * 1024 + cl * 8;
  const bf16* aop1 = A + (size_t)(m0 + 128 + srow) * 1024 + cl * 8;
  const bf16* bop0 = BT + (size_t)(n0 + srow) * 1024 + cl * 8;
  const bf16* bop1 = BT + (size_t)(n0 + 128 + srow) * 1024 + cl * 8;
  const int wd0 = wave * 512;
  const int wd1 = 4096 + wave * 512;

  const int fc = (kq ^ ((lr ^ (lr >> 2)) & 3)) * 8;
  const int arow = wm * 128 + lr;
  const int brow = wn * 64 + lr;

  const f32x4 zero = {0.f, 0.f, 0.f, 0.f};
  f32x4 acc[8][4];
  #pragma unroll
  for (int i = 0; i < 8; i++)
    #pragma unroll
    for (int j = 0; j < 4; j++) acc[i][j] = zero;

  gemm_mainloop_256(aop0, aop1, bop0, bop1, sm.a, sm.b, wd0, wd1,
                    arow, brow, fc, acc);

  float bv[4];
  #pragma unroll
  for (int j = 0; j < 4; j++) bv[j] = bias[n0 + wn * 64 + j * 16 + lr];
  #pragma unroll
  for (int i = 0; i < 8; i++) {
    const int row0 = m0 + wm * 128 + i * 16 + kq * 4;
    #pragma unroll
    for (int j = 0; j < 4; j++) {
      const int col = n0 + wn * 64 + j * 16 + lr;
      #pragma unroll
      for (int r2 = 0; r2 < 4; r2++)
        C[(size_t)(row0 + r2) * 1024 + col] = acc[i][j][r2] + bv[j];
    }
  }
}

// ---------------------------------------------------------------------------------
extern "C" void kernel_launch(void* const* d_in, const int* in_sizes, int n_in,
                              void* d_out, int out_size, void* d_ws, size_t ws_size,
                              hipStream_t stream) {
  (void)in_sizes; (void)n_in; (void)out_size; (void)ws_size;
  const float* x    = (const float*)d_in[0];
  const float* Wq   = (const float*)d_in[1];
  const float* Wkv  = (const float*)d_in[2];
  const float* Wlin = (const float*)d_in[3];
  const float* blin = (const float*)d_in[4];
  float* out = (float*)d_out;              // reference output dtype = float32

  // workspace layout (~160 MB total)
  bf16* x_bf  = (bf16*)d_ws;                  // 33,554,432
  bf16* WTc   = x_bf + 33554432;              // 3,145,728   [Wq^T | Wkv^T]
  bf16* WlinT = WTc + 3145728;                // 1,048,576
  bf16* Yq    = WlinT + 1048576;              // 33,554,432  (q only)
  bf16* W2T   = Yq + 33554432;                // 8,388,608
  float* ctxAcc = (float*)(W2T + 8388608);    // 128 * 4160 fp32 (R | Z)

  cast_f32_bf16<<<16384, 256, 0, stream>>>(x, x_bf, 33554432LL);
  tcast<<<dim3(32, 32), dim3(32, 8), 0, stream>>>(Wq, WTc, 1024, 1024);
  tcast<<<dim3(64, 32), dim3(32, 8), 0, stream>>>(Wkv, WTc + 1048576, 1024, 2048);
  tcast<<<dim3(32, 32), dim3(32, 8), 0, stream>>>(Wlin, WlinT, 1024, 1024);

  hipMemsetAsync(ctxAcc, 0, (size_t)128 * 4160 * sizeof(float), stream);

  gemm_qkv<<<dim3(128 * QKV_NT), 512, 0, stream>>>(x_bf, WTc, Yq, ctxAcc);
  make_w2t<<<dim3(16, 128), 256, 0, stream>>>(ctxAcc, WlinT, W2T);
  gemm_out<<<dim3(512), 512, 0, stream>>>(Yq, W2T, out, blin);
}

// Round 4
// 390.770 us; speedup vs baseline: 1.3183x; 1.0323x over previous
//
#include <hip/hip_runtime.h>
#include <hip/hip_bf16.h>
#include <cstdint>

using bf16 = __hip_bfloat16;
typedef __attribute__((ext_vector_type(8))) short bf16x8;
typedef __attribute__((ext_vector_type(4))) float f32x4;

struct alignas(16) B8 { bf16 h[8]; };
struct alignas(8)  B4 { bf16 h[4]; };

__device__ __forceinline__ void gll16(const void* g, void* l) {
  __builtin_amdgcn_global_load_lds((__attribute__((address_space(1))) void*)g,
                                   (__attribute__((address_space(3))) void*)l,
                                   16, 0, 0);
}

// ---------------- cast fp32 -> bf16 (vectorized) ----------------
__global__ void cast_f32_bf16(const float* __restrict__ in, bf16* __restrict__ out, long long n) {
  long long i = ((long long)blockIdx.x * blockDim.x + threadIdx.x) * 8;
  if (i >= n) return;
  float4 v0 = *(const float4*)(in + i);
  float4 v1 = *(const float4*)(in + i + 4);
  B8 o;
  o.h[0] = __float2bfloat16(v0.x); o.h[1] = __float2bfloat16(v0.y);
  o.h[2] = __float2bfloat16(v0.z); o.h[3] = __float2bfloat16(v0.w);
  o.h[4] = __float2bfloat16(v1.x); o.h[5] = __float2bfloat16(v1.y);
  o.h[6] = __float2bfloat16(v1.z); o.h[7] = __float2bfloat16(v1.w);
  *(B8*)(out + i) = o;
}

// ---------------- transpose + cast: W[K][N] fp32 -> WT[N][K] bf16 ----------------
__global__ void tcast(const float* __restrict__ W, bf16* __restrict__ WT, int K, int N) {
  __shared__ float tile[32][33];
  int k0 = blockIdx.y * 32, n0 = blockIdx.x * 32;
  int tx = threadIdx.x, ty = threadIdx.y;  // block (32,8)
  for (int yy = ty; yy < 32; yy += 8)
    tile[yy][tx] = W[(size_t)(k0 + yy) * N + n0 + tx];
  __syncthreads();
  for (int yy = ty; yy < 32; yy += 8)
    WT[(size_t)(n0 + yy) * K + k0 + tx] = __float2bfloat16(tile[tx][yy]);
}

// =================================================================================
// Shared 256x256-tile, BK=64, 8-wave pipelined main loop (K=1024 fixed).
//  - LDS ring of 4 half-K slots per operand (256 rows x 32 k, 16KB each), 128KB.
//  - 2 sections per K-tile (one per 32-k half): ONE barrier + ONE counted vmcnt
//    per section (was 2 barriers per phase = 8/kt). Layout per section:
//      vmcnt(4) -> barrier -> stage A-half -> ds_read B+A(i0-3) -> lgkm(0) ->
//      MFMA cluster 1 (interleaved in-place ds_read of A(i4-7) into a[i]) ->
//      stage B-half -> lgkm(0) -> MFMA cluster 2.
//    Cluster-1 MFMA hides cluster-2's LDS drain; stages stay >=1 kt ahead with
//    4-8 loads always in flight (vmcnt(0) only on the very last section).
//  - Slot-hazard audit: slot staged at (kt,h) is read at (kt+1,h); its previous
//    readers finished (own lgkm(0)) before MFMA at (kt-1,h), which precedes the
//    (kt,h) barrier every wave crossed before staging. Single barrier suffices.
//  - chunk-XOR swizzle: physical 16B chunk = logical ^ ((row^(row>>2))&3), applied
//    by pre-swizzling the GLOBAL source address (LDS dest linear, as
//    global_load_lds requires) and the matching XOR on ds_read addresses.
// =================================================================================
__device__ __forceinline__ void gemm_mainloop_256(
    const bf16* __restrict__ aop0, const bf16* __restrict__ aop1,
    const bf16* __restrict__ bop0, const bf16* __restrict__ bop1,
    bf16* ldsA, bf16* ldsB, int wd0, int wd1,
    int arow, int brow, int fc, f32x4 (&acc)[8][4])
{
#define STAGE_A(slot, ko) do { gll16(aop0 + (ko), ldsA + (slot) * 8192 + wd0); \
                               gll16(aop1 + (ko), ldsA + (slot) * 8192 + wd1); } while (0)
#define STAGE_B(slot, ko) do { gll16(bop0 + (ko), ldsB + (slot) * 8192 + wd0); \
                               gll16(bop1 + (ko), ldsB + (slot) * 8192 + wd1); } while (0)
#define AFRAG(slot, i) (*(const bf16x8*)(ldsA + (slot) * 8192 + (arow + (i) * 16) * 32 + fc))
#define BFRAG(slot, j) (*(const bf16x8*)(ldsB + (slot) * 8192 + (brow + (j) * 16) * 32 + fc))

  // prologue: tile 0 -> slots {0,1}; FIFO order matters for counted vmcnt.
  STAGE_A(0, 0); STAGE_B(0, 0);
  STAGE_A(1, 32); STAGE_B(1, 32);

  #pragma unroll 2
  for (int kt = 0; kt < 16; ++kt) {
    const bool more = kt < 15;
    #pragma unroll
    for (int h = 0; h < 2; ++h) {
      const int sh = (2 * kt + h) & 3;          // slot consumed this section
      const int ph = (2 * kt + 2 + h) & 3;      // slot staged this section (kt+1)
      const int ko = (kt + 1) * 64 + h * 32;

      // verify slot sh: 4 oldest in-flight loads are sh's (8 outstanding in
      // steady state). Last section has only 4 outstanding -> full drain.
      if (more || h == 0) { asm volatile("s_waitcnt vmcnt(4)" ::: "memory"); }
      else               { asm volatile("s_waitcnt vmcnt(0)" ::: "memory"); }
      __builtin_amdgcn_s_barrier();
      __builtin_amdgcn_sched_barrier(0);

      if (more) STAGE_A(ph, ko);

      bf16x8 a[4], b[4];
      #pragma unroll
      for (int j = 0; j < 4; j++) b[j] = BFRAG(sh, j);
      #pragma unroll
      for (int i = 0; i < 4; i++) a[i] = AFRAG(sh, i);
      asm volatile("s_waitcnt lgkmcnt(0)" ::: "memory");
      __builtin_amdgcn_sched_barrier(0);

      __builtin_amdgcn_s_setprio(1);
      #pragma unroll
      for (int i = 0; i < 4; i++) {
        #pragma unroll
        for (int j = 0; j < 4; j++)
          acc[i][j] = __builtin_amdgcn_mfma_f32_16x16x32_bf16(a[i], b[j], acc[i][j], 0, 0, 0);
        a[i] = AFRAG(sh, i + 4);    // in-place replacement read, hidden under MFMA
      }
      __builtin_amdgcn_s_setprio(0);

      if (more) STAGE_B(ph, ko);
      asm volatile("s_waitcnt lgkmcnt(0)" ::: "memory");
      __builtin_amdgcn_sched_barrier(0);

      __builtin_amdgcn_s_setprio(1);
      #pragma unroll
      for (int i = 0; i < 4; i++)
        #pragma unroll
        for (int j = 0; j < 4; j++)
          acc[i + 4][j] = __builtin_amdgcn_mfma_f32_16x16x32_bf16(a[i], b[j], acc[i + 4][j], 0, 0, 0);
      __builtin_amdgcn_s_setprio(0);
    }
  }
  __syncthreads();   // all frag reads done before epilogues reuse/overwrite LDS
#undef STAGE_A
#undef STAGE_B
#undef AFRAG
#undef BFRAG
}

// =================================================================================
// Fused QKV GEMM:  T = x_bf @ [Wq | Wkv]  (M=32768, N=3072, K=1024)
//  - XCD-chunked block swizzle: 1536 blocks = 8 XCDs x 192 (bm-major per XCD).
//  - q tiles (bn<4): per-row softmax over the wave's 64-col head slice (* DH^-0.5).
//  - kv tiles: 2 heads/block. exp(k), v -> swizzled LDS [64][256] via b64 writes;
//    Z from registers (shfl reduce); R[d][e] partial via MFMA; fp32 atomics.
// =================================================================================
constexpr int QKV_NT = 12;   // N/256

__global__ __launch_bounds__(512, 2)
void gemm_qkv(const bf16* __restrict__ A, const bf16* __restrict__ BT,
              bf16* __restrict__ Yq, float* __restrict__ ctxAcc)
{
  __shared__ __align__(16) union {
    struct { bf16 a[4 * 8192]; bf16 b[4 * 8192]; } g;       // 4+4 slots (16KB each)
    struct { bf16 ekT[2][16384]; bf16 vT[2][16384]; } c;    // kv epilogue (swizzled [64][256])
  } sm;

  const int t = threadIdx.x;
  const int wave = t >> 6, lane = t & 63;
  const int lr = lane & 15, kq = lane >> 4;
  const int wm = wave >> 2, wn = wave & 3;
  // XCD-chunked swizzle (bijective: 1536 = 8 * 192; dispatch round-robins bid%8)
  const int bid = (int)blockIdx.x;
  const int swz = (bid & 7) * 192 + (bid >> 3);
  const int bm = swz / QKV_NT, bn = swz % QKV_NT;
  const int m0 = bm * 256, n0 = bn * 256;

  // ---- staging constants: thread covers physical chunks t and t+512 of each half
  const int srow = t >> 2;                                   // 0..127
  const int cl = (t & 3) ^ ((srow ^ (srow >> 2)) & 3);       // logical k-chunk
  const bf16* aop0 = A + (size_t)(m0 + srow) * 1024 + cl * 8;
  const bf16* aop1 = A + (size_t)(m0 + 128 + srow) * 1024 + cl * 8;
  const bf16* bop0 = BT + (size_t)(n0 + srow) * 1024 + cl * 8;
  const bf16* bop1 = BT + (size_t)(n0 + 128 + srow) * 1024 + cl * 8;
  const int wd0 = wave * 512;          // elems, wave-uniform dest (gll writes base+lane*16)
  const int wd1 = 4096 + wave * 512;

  // ---- fragment-read constants (swizzled chunk is a pure lane constant)
  const int fc = (kq ^ ((lr ^ (lr >> 2)) & 3)) * 8;          // elems
  const int arow = wm * 128 + lr;
  const int brow = wn * 64 + lr;

  const f32x4 zero = {0.f, 0.f, 0.f, 0.f};
  f32x4 acc[8][4];
  #pragma unroll
  for (int i = 0; i < 8; i++)
    #pragma unroll
    for (int j = 0; j < 4; j++) acc[i][j] = zero;

  gemm_mainloop_256(aop0, aop1, bop0, bop1, sm.g.a, sm.g.b, wd0, wd1,
                    arow, brow, fc, acc);

  if (bn < 4) {
    // ---- fused q softmax: each wave's 64 cols = one head ----
    #pragma unroll
    for (int i = 0; i < 8; i++) {
      #pragma unroll
      for (int r = 0; r < 4; r++) {
        float m = fmaxf(fmaxf(acc[i][0][r], acc[i][1][r]),
                        fmaxf(acc[i][2][r], acc[i][3][r]));
        m = fmaxf(m, __shfl_xor(m, 1));
        m = fmaxf(m, __shfl_xor(m, 2));
        m = fmaxf(m, __shfl_xor(m, 4));
        m = fmaxf(m, __shfl_xor(m, 8));
        float ex[4]; float s = 0.f;
        #pragma unroll
        for (int j = 0; j < 4; j++) { ex[j] = __expf(acc[i][j][r] - m); s += ex[j]; }
        s += __shfl_xor(s, 1);
        s += __shfl_xor(s, 2);
        s += __shfl_xor(s, 4);
        s += __shfl_xor(s, 8);
        const float inv = 0.125f / s;           // scale = DH^-0.5
        const int row = m0 + wm * 128 + i * 16 + kq * 4 + r;
        bf16* yrow = Yq + (size_t)row * 1024 + n0 + wn * 64;
        #pragma unroll
        for (int j = 0; j < 4; j++)
          yrow[j * 16 + lr] = __float2bfloat16(ex[j] * inv);
      }
    }
  } else {
    // ---- fused context: tile = 256 s-rows x 2 heads (each head: 64 k | 64 v) ----
    const int bb = m0 >> 12;                  // batch (4096 rows per batch)
    const int h0 = (n0 - 1024) >> 7;          // first head of this tile
    const int hloc = wn >> 1, isV = wn & 1;   // wave role
    bf16* const dstT = (isV ? sm.c.vT[hloc] : sm.c.ekT[hloc]);

    float zp[4] = {0.f, 0.f, 0.f, 0.f};
    #pragma unroll
    for (int i = 0; i < 8; i++) {
      const int sbase = wm * 128 + i * 16 + kq * 4;
      const int sxo = sbase >> 3;             // chunk (constant across r)
      const int sby = (sbase & 7) * 2;        // byte offset within chunk (0 or 8)
      #pragma unroll
      for (int j = 0; j < 4; j++) {
        const int d = j * 16 + lr;
        B4 pk;
        if (!isV) {
          #pragma unroll
          for (int r = 0; r < 4; r++) {
            float e = __expf(acc[i][j][r]);
            zp[j] += e;
            pk.h[r] = __float2bfloat16(e);
          }
        } else {
          #pragma unroll
          for (int r = 0; r < 4; r++) pk.h[r] = __float2bfloat16(acc[i][j][r]);
        }
        *(B4*)((char*)dstT + d * 512 + ((sxo ^ (d & 7)) << 4) + sby) = pk;
      }
    }

    if (!isV) {
      // Z[d] partial over this wave's 128 s-rows, straight from registers
      #pragma unroll
      for (int j = 0; j < 4; j++) {
        zp[j] += __shfl_xor(zp[j], 16);
        zp[j] += __shfl_xor(zp[j], 32);
      }
      if (kq == 0) {
        float* zb = ctxAcc + (size_t)(bb * 16 + h0 + hloc) * 4160 + 4096;
        #pragma unroll
        for (int j = 0; j < 4; j++) atomicAdd(zb + j * 16 + lr, zp[j]);
      }
    }
    __syncthreads();

    // R[d][e] partial via MFMA over K=256 s-rows; wave -> (head = wave>>2, d-quad = wave&3)
    const int hh = wave >> 2, dq = wave & 3;
    const bf16* const ek = sm.c.ekT[hh];
    const bf16* const vv = sm.c.vT[hh];
    f32x4 racc[4] = {zero, zero, zero, zero};
    #pragma unroll
    for (int ks = 0; ks < 8; ks++) {
      const int ch = ks * 4 + kq;
      bf16x8 af = *(const bf16x8*)((const char*)ek + (dq * 16 + lr) * 512 + ((ch ^ (lr & 7)) << 4));
      #pragma unroll
      for (int j = 0; j < 4; j++) {
        bf16x8 bfr = *(const bf16x8*)((const char*)vv + (j * 16 + lr) * 512 + ((ch ^ (lr & 7)) << 4));
        racc[j] = __builtin_amdgcn_mfma_f32_16x16x32_bf16(af, bfr, racc[j], 0, 0, 0);
      }
    }
    float* cb = ctxAcc + (size_t)(bb * 16 + h0 + hh) * 4160;
    #pragma unroll
    for (int j = 0; j < 4; j++) {
      #pragma unroll
      for (int r = 0; r < 4; r++)
        atomicAdd(cb + (dq * 16 + kq * 4 + r) * 64 + j * 16 + lr, racc[j][r]);
    }
  }
}

// ---------------- W2T[b][n][h*64+d] = sum_e (R[bh][d][e]/Z[bh][d]) * WlinT[n][h*64+e]
// (ctx normalization folded in; reads fp32 ctxAcc directly)
__global__ __launch_bounds__(256) void make_w2t(const float* __restrict__ ctxAcc,
                                                const bf16* __restrict__ WlinT,
                                                bf16* __restrict__ W2T) {
  const int nc = blockIdx.x;      // 0..15
  const int bh = blockIdx.y;      // 0..127
  const int b = bh >> 4, h = bh & 15;
  const int t = threadIdx.x, lane = t & 63, w = t >> 6;
  const float* src = ctxAcc + (size_t)bh * 4160;
  const float invz = 1.0f / src[4096 + lane];   // Z[d], d = lane
  float creg[64];
  const float* crow = src + lane * 64;
  #pragma unroll
  for (int e4 = 0; e4 < 16; e4++) {
    float4 v = *(const float4*)(crow + e4 * 4);
    creg[e4 * 4 + 0] = v.x * invz; creg[e4 * 4 + 1] = v.y * invz;
    creg[e4 * 4 + 2] = v.z * invz; creg[e4 * 4 + 3] = v.w * invz;
  }
  for (int i = 0; i < 16; i++) {
    const int n = nc * 64 + w * 16 + i;
    const bf16* wrow = WlinT + (size_t)n * 1024 + h * 64;
    float acc = 0.f;
    #pragma unroll
    for (int e8 = 0; e8 < 8; e8++) {
      B8 v = *(const B8*)(wrow + e8 * 8);
      #pragma unroll
      for (int j = 0; j < 8; j++) acc += creg[e8 * 8 + j] * __bfloat162float(v.h[j]);
    }
    W2T[((size_t)b * 1024 + n) * 1024 + h * 64 + lane] = __float2bfloat16(acc);
  }
}

// ---------------- out[b] = Yq[b] @ W2T[b]^T + blin, fp32 output -------------------
// per batch: M=4096, N=1024, K=1024; 256x256 tiles, pipelined main loop; grid 512
// XCD-chunked swizzle: each XCD owns one batch (64 blocks): W2T[b] (2MB) L2-resident.
__global__ __launch_bounds__(512, 2)
void gemm_out(const bf16* __restrict__ Aall, const bf16* __restrict__ BTall,
              float* __restrict__ Call, const float* __restrict__ bias)
{
  __shared__ __align__(16) struct { bf16 a[4 * 8192]; bf16 b[4 * 8192]; } sm;
  const int t = threadIdx.x;
  const int wave = t >> 6, lane = t & 63;
  const int lr = lane & 15, kq = lane >> 4;
  const int wm = wave >> 2, wn = wave & 3;
  // bijective XCD swizzle: 512 = 8 * 64; XCD x -> batch x
  const int bid = (int)blockIdx.x;
  const int swz = (bid & 7) * 64 + (bid >> 3);
  const int bz = swz >> 6;
  const int r  = swz & 63;
  const int bm = r >> 2, bn = r & 3;
  const int m0 = bm * 256, n0 = bn * 256;
  const bf16* A  = Aall  + (size_t)bz * 4096 * 1024;
  const bf16* BT = BTall + (size_t)bz * 1024 * 1024;
  float* C       = Call  + (size_t)bz * 4096 * 1024;

  const int srow = t >> 2;
  const int cl = (t & 3) ^ ((srow ^ (srow >> 2)) & 3);
  const bf16* aop0 = A + (size_t)(m0 + srow) * 1024 + cl * 8;
  const bf16* aop1 = A + (size_t)(m0 + 128 + srow) * 1024 + cl * 8;
  const bf16* bop0 = BT + (size_t)(n0 + srow) * 1024 + cl * 8;
  const bf16* bop1 = BT + (size_t)(n0 + 128 + srow) * 1024 + cl * 8;
  const int wd0 = wave * 512;
  const int wd1 = 4096 + wave * 512;

  const int fc = (kq ^ ((lr ^ (lr >> 2)) & 3)) * 8;
  const int arow = wm * 128 + lr;
  const int brow = wn * 64 + lr;

  const f32x4 zero = {0.f, 0.f, 0.f, 0.f};
  f32x4 acc[8][4];
  #pragma unroll
  for (int i = 0; i < 8; i++)
    #pragma unroll
    for (int j = 0; j < 4; j++) acc[i][j] = zero;

  gemm_mainloop_256(aop0, aop1, bop0, bop1, sm.a, sm.b, wd0, wd1,
                    arow, brow, fc, acc);

  float bv[4];
  #pragma unroll
  for (int j = 0; j < 4; j++) bv[j] = bias[n0 + wn * 64 + j * 16 + lr];
  #pragma unroll
  for (int i = 0; i < 8; i++) {
    const int row0 = m0 + wm * 128 + i * 16 + kq * 4;
    #pragma unroll
    for (int j = 0; j < 4; j++) {
      const int col = n0 + wn * 64 + j * 16 + lr;
      const float bvj = bv[j];
      #pragma unroll
      for (int r2 = 0; r2 < 4; r2++)
        C[(size_t)(row0 + r2) * 1024 + col] = acc[i][j][r2] + bvj;
    }
  }
}

// ---------------------------------------------------------------------------------
extern "C" void kernel_launch(void* const* d_in, const int* in_sizes, int n_in,
                              void* d_out, int out_size, void* d_ws, size_t ws_size,
                              hipStream_t stream) {
  (void)in_sizes; (void)n_in; (void)out_size; (void)ws_size;
  const float* x    = (const float*)d_in[0];
  const float* Wq   = (const float*)d_in[1];
  const float* Wkv  = (const float*)d_in[2];
  const float* Wlin = (const float*)d_in[3];
  const float* blin = (const float*)d_in[4];
  float* out = (float*)d_out;              // reference output dtype = float32

  // workspace layout (~160 MB total)
  bf16* x_bf  = (bf16*)d_ws;                  // 33,554,432
  bf16* WTc   = x_bf + 33554432;              // 3,145,728   [Wq^T | Wkv^T]
  bf16* WlinT = WTc + 3145728;                // 1,048,576
  bf16* Yq    = WlinT + 1048576;              // 33,554,432  (q only)
  bf16* W2T   = Yq + 33554432;                // 8,388,608
  float* ctxAcc = (float*)(W2T + 8388608);    // 128 * 4160 fp32 (R | Z)

  cast_f32_bf16<<<16384, 256, 0, stream>>>(x, x_bf, 33554432LL);
  tcast<<<dim3(32, 32), dim3(32, 8), 0, stream>>>(Wq, WTc, 1024, 1024);
  tcast<<<dim3(64, 32), dim3(32, 8), 0, stream>>>(Wkv, WTc + 1048576, 1024, 2048);
  tcast<<<dim3(32, 32), dim3(32, 8), 0, stream>>>(Wlin, WlinT, 1024, 1024);

  hipMemsetAsync(ctxAcc, 0, (size_t)128 * 4160 * sizeof(float), stream);

  gemm_qkv<<<dim3(128 * QKV_NT), 512, 0, stream>>>(x_bf, WTc, Yq, ctxAcc);
  make_w2t<<<dim3(16, 128), 256, 0, stream>>>(ctxAcc, WlinT, W2T);
  gemm_out<<<dim3(512), 512, 0, stream>>>(Yq, W2T, out, blin);
}

// Round 5
// 389.838 us; speedup vs baseline: 1.3215x; 1.0024x over previous
//
#include <hip/hip_runtime.h>
#include <hip/hip_bf16.h>
#include <cstdint>

using bf16 = __hip_bfloat16;
typedef __attribute__((ext_vector_type(8))) short bf16x8;
typedef __attribute__((ext_vector_type(4))) float f32x4;

struct alignas(16) B8 { bf16 h[8]; };
struct alignas(8)  B4 { bf16 h[4]; };

__device__ __forceinline__ void gll16(const void* g, void* l) {
  __builtin_amdgcn_global_load_lds((__attribute__((address_space(1))) void*)g,
                                   (__attribute__((address_space(3))) void*)l,
                                   16, 0, 0);
}

// ---------------- cast fp32 -> bf16 (vectorized) ----------------
__global__ void cast_f32_bf16(const float* __restrict__ in, bf16* __restrict__ out, long long n) {
  long long i = ((long long)blockIdx.x * blockDim.x + threadIdx.x) * 8;
  if (i >= n) return;
  float4 v0 = *(const float4*)(in + i);
  float4 v1 = *(const float4*)(in + i + 4);
  B8 o;
  o.h[0] = __float2bfloat16(v0.x); o.h[1] = __float2bfloat16(v0.y);
  o.h[2] = __float2bfloat16(v0.z); o.h[3] = __float2bfloat16(v0.w);
  o.h[4] = __float2bfloat16(v1.x); o.h[5] = __float2bfloat16(v1.y);
  o.h[6] = __float2bfloat16(v1.z); o.h[7] = __float2bfloat16(v1.w);
  *(B8*)(out + i) = o;
}

// ---------------- transpose + cast: W[K][N] fp32 -> WT[N][K] bf16 ----------------
__global__ void tcast(const float* __restrict__ W, bf16* __restrict__ WT, int K, int N) {
  __shared__ float tile[32][33];
  int k0 = blockIdx.y * 32, n0 = blockIdx.x * 32;
  int tx = threadIdx.x, ty = threadIdx.y;  // block (32,8)
  for (int yy = ty; yy < 32; yy += 8)
    tile[yy][tx] = W[(size_t)(k0 + yy) * N + n0 + tx];
  __syncthreads();
  for (int yy = ty; yy < 32; yy += 8)
    WT[(size_t)(n0 + yy) * K + k0 + tx] = __float2bfloat16(tile[tx][yy]);
}

// =================================================================================
// Shared 256x256-tile, BK=32-per-section, 8-wave pipelined main loop (K=1024).
// 32 sections; LDS ring of 4 slots/operand (256r x 32k, 16KB), staged 3 AHEAD:
//   boundary into v:  vmcnt(4) -> s_barrier -> stage slot (v+3)&3 (4 gll16).
//   section u:        lgkm(0) -> MFMA rows0-3 (interleave a2 = A rows4-7 reads)
//                     -> lgkm(0) -> MFMA rows4-7 (interleave PREFETCH of section
//                        u+1's B (into bb[(u+1)&1]) and A rows0-3 (in-place a1)).
// The prefetch puts every section's first-batch LDS drain UNDER the previous
// section's MFMA cluster -> LDS and MFMA pipes overlap instead of alternating.
// Write-safety: reads of slot S issued after the vmcnt+barrier that retired S's
// stage (own-wave vmcnt before barrier => cross-wave visibility after barrier).
// Slot lifetime: staged@boundary(v-3) -> retired@vmcnt(boundary v-1) -> read
// (prefetch) during section v-1 -> last a2-read during section v, drained by
// lgkm before MFMA2(v) < barrier(v+1) <= next overwrite @boundary(v+1).
// chunk-XOR swizzle unchanged: phys 16B chunk = logical ^ ((row^(row>>2))&3),
// pre-swizzled global source (linear LDS dest) + same XOR on ds_read.
// =================================================================================
__device__ __forceinline__ void gemm_mainloop_256(
    const bf16* __restrict__ aop0, const bf16* __restrict__ aop1,
    const bf16* __restrict__ bop0, const bf16* __restrict__ bop1,
    bf16* ldsA, bf16* ldsB, int wd0, int wd1,
    int arow, int brow, int fc, f32x4 (&acc)[8][4])
{
#define STAGE_A(slot, ko) do { gll16(aop0 + (ko), ldsA + (slot) * 8192 + wd0); \
                               gll16(aop1 + (ko), ldsA + (slot) * 8192 + wd1); } while (0)
#define STAGE_B(slot, ko) do { gll16(bop0 + (ko), ldsB + (slot) * 8192 + wd0); \
                               gll16(bop1 + (ko), ldsB + (slot) * 8192 + wd1); } while (0)
#define AFRAG(slot, i) (*(const bf16x8*)(ldsA + (slot) * 8192 + (arow + (i) * 16) * 32 + fc))
#define BFRAG(slot, j) (*(const bf16x8*)(ldsB + (slot) * 8192 + (brow + (j) * 16) * 32 + fc))

  bf16x8 a1[4], a2[4], bb[2][4];

#define SECTION(S, CURB, NXTB, DO_PF, PFS)                                          \
  do {                                                                              \
    asm volatile("s_waitcnt lgkmcnt(0)" ::: "memory");                              \
    __builtin_amdgcn_sched_barrier(0);                                              \
    __builtin_amdgcn_s_setprio(1);                                                  \
    _Pragma("unroll")                                                               \
    for (int i = 0; i < 4; i++) {                                                   \
      _Pragma("unroll")                                                             \
      for (int j = 0; j < 4; j++)                                                   \
        acc[i][j] = __builtin_amdgcn_mfma_f32_16x16x32_bf16(a1[i], bb[CURB][j],     \
                                                            acc[i][j], 0, 0, 0);    \
      a2[i] = AFRAG(S, i + 4);                                                      \
    }                                                                               \
    asm volatile("s_waitcnt lgkmcnt(0)" ::: "memory");                              \
    __builtin_amdgcn_sched_barrier(0);                                              \
    _Pragma("unroll")                                                               \
    for (int i = 0; i < 4; i++) {                                                   \
      _Pragma("unroll")                                                             \
      for (int j = 0; j < 4; j++)                                                   \
        acc[i + 4][j] = __builtin_amdgcn_mfma_f32_16x16x32_bf16(a2[i], bb[CURB][j], \
                                                                acc[i + 4][j], 0, 0, 0); \
      if (DO_PF) { bb[NXTB][i] = BFRAG(PFS, i); a1[i] = AFRAG(PFS, i); }            \
    }                                                                               \
    __builtin_amdgcn_s_setprio(0);                                                  \
  } while (0)

#define BOUNDARY(VMC, DO_STAGE, SLOT, KO)                                           \
  do {                                                                              \
    asm volatile("s_waitcnt vmcnt(" #VMC ")" ::: "memory");                         \
    __builtin_amdgcn_s_barrier();                                                   \
    __builtin_amdgcn_sched_barrier(0);                                              \
    if (DO_STAGE) { STAGE_A(SLOT, KO); STAGE_B(SLOT, KO); }                         \
  } while (0)

  // prologue: sections 0,1,2 staged; slot 0 resident before first reads
  STAGE_A(0, 0);  STAGE_B(0, 0);
  STAGE_A(1, 32); STAGE_B(1, 32);
  STAGE_A(2, 64); STAGE_B(2, 64);
  asm volatile("s_waitcnt vmcnt(8)" ::: "memory");
  __builtin_amdgcn_s_barrier();
  __builtin_amdgcn_sched_barrier(0);
  STAGE_A(3, 96); STAGE_B(3, 96);          // boundary-into-0 stage (section 3)
  #pragma unroll
  for (int j = 0; j < 4; j++) bb[0][j] = BFRAG(0, j);
  #pragma unroll
  for (int i = 0; i < 4; i++) a1[i] = AFRAG(0, i);

  // sections 0..27 (7 x 4); boundary into v stages section v+3 at ko=(v+3)*32
  for (int q = 0; q < 7; ++q) {
    const int ko = q * 128 + 128;
    SECTION(0, 0, 1, true, 1);
    BOUNDARY(4, true, 0, ko);
    SECTION(1, 1, 0, true, 2);
    BOUNDARY(4, true, 1, ko + 32);
    SECTION(2, 0, 1, true, 3);
    BOUNDARY(4, true, 2, ko + 64);
    SECTION(3, 1, 0, true, 0);
    BOUNDARY(4, true, 3, ko + 96);
  }
  // tail: sections 28..31 (all data staged; drain ring)
  SECTION(0, 0, 1, true, 1);
  BOUNDARY(4, false, 0, 0);
  SECTION(1, 1, 0, true, 2);
  BOUNDARY(0, false, 0, 0);
  SECTION(2, 0, 1, true, 3);
  BOUNDARY(0, false, 0, 0);
  SECTION(3, 1, 0, false, 0);

  __syncthreads();   // all frag reads done before epilogues reuse/overwrite LDS
#undef SECTION
#undef BOUNDARY
#undef STAGE_A
#undef STAGE_B
#undef AFRAG
#undef BFRAG
}

// =================================================================================
// Fused QKV GEMM:  T = x_bf @ [Wq | Wkv]  (M=32768, N=3072, K=1024)
//  - XCD-chunked block swizzle: 1536 blocks = 8 XCDs x 192 (bm-major per XCD).
//  - q tiles (bn<4): per-row softmax over the wave's 64-col head slice (* DH^-0.5).
//  - kv tiles: 2 heads/block. exp(k), v -> swizzled LDS [64][256] via b64 writes;
//    Z from registers (shfl reduce); R[d][e] partial via MFMA; fp32 atomics.
// =================================================================================
constexpr int QKV_NT = 12;   // N/256

__global__ __launch_bounds__(512, 2)
void gemm_qkv(const bf16* __restrict__ A, const bf16* __restrict__ BT,
              bf16* __restrict__ Yq, float* __restrict__ ctxAcc)
{
  __shared__ __align__(16) union {
    struct { bf16 a[4 * 8192]; bf16 b[4 * 8192]; } g;       // 4+4 slots (16KB each)
    struct { bf16 ekT[2][16384]; bf16 vT[2][16384]; } c;    // kv epilogue (swizzled [64][256])
  } sm;

  const int t = threadIdx.x;
  const int wave = t >> 6, lane = t & 63;
  const int lr = lane & 15, kq = lane >> 4;
  const int wm = wave >> 2, wn = wave & 3;
  // XCD-chunked swizzle (bijective: 1536 = 8 * 192; dispatch round-robins bid%8)
  const int bid = (int)blockIdx.x;
  const int swz = (bid & 7) * 192 + (bid >> 3);
  const int bm = swz / QKV_NT, bn = swz % QKV_NT;
  const int m0 = bm * 256, n0 = bn * 256;

  // ---- staging constants: thread covers physical chunks t and t+512 of each half
  const int srow = t >> 2;                                   // 0..127
  const int cl = (t & 3) ^ ((srow ^ (srow >> 2)) & 3);       // logical k-chunk
  const bf16* aop0 = A + (size_t)(m0 + srow) * 1024 + cl * 8;
  const bf16* aop1 = A + (size_t)(m0 + 128 + srow) * 1024 + cl * 8;
  const bf16* bop0 = BT + (size_t)(n0 + srow) * 1024 + cl * 8;
  const bf16* bop1 = BT + (size_t)(n0 + 128 + srow) * 1024 + cl * 8;
  const int wd0 = wave * 512;          // elems, wave-uniform dest (gll writes base+lane*16)
  const int wd1 = 4096 + wave * 512;

  // ---- fragment-read constants (swizzled chunk is a pure lane constant)
  const int fc = (kq ^ ((lr ^ (lr >> 2)) & 3)) * 8;          // elems
  const int arow = wm * 128 + lr;
  const int brow = wn * 64 + lr;

  const f32x4 zero = {0.f, 0.f, 0.f, 0.f};
  f32x4 acc[8][4];
  #pragma unroll
  for (int i = 0; i < 8; i++)
    #pragma unroll
    for (int j = 0; j < 4; j++) acc[i][j] = zero;

  gemm_mainloop_256(aop0, aop1, bop0, bop1, sm.g.a, sm.g.b, wd0, wd1,
                    arow, brow, fc, acc);

  if (bn < 4) {
    // ---- fused q softmax: each wave's 64 cols = one head ----
    #pragma unroll
    for (int i = 0; i < 8; i++) {
      #pragma unroll
      for (int r = 0; r < 4; r++) {
        float m = fmaxf(fmaxf(acc[i][0][r], acc[i][1][r]),
                        fmaxf(acc[i][2][r], acc[i][3][r]));
        m = fmaxf(m, __shfl_xor(m, 1));
        m = fmaxf(m, __shfl_xor(m, 2));
        m = fmaxf(m, __shfl_xor(m, 4));
        m = fmaxf(m, __shfl_xor(m, 8));
        float ex[4]; float s = 0.f;
        #pragma unroll
        for (int j = 0; j < 4; j++) { ex[j] = __expf(acc[i][j][r] - m); s += ex[j]; }
        s += __shfl_xor(s, 1);
        s += __shfl_xor(s, 2);
        s += __shfl_xor(s, 4);
        s += __shfl_xor(s, 8);
        const float inv = 0.125f / s;           // scale = DH^-0.5
        const int row = m0 + wm * 128 + i * 16 + kq * 4 + r;
        bf16* yrow = Yq + (size_t)row * 1024 + n0 + wn * 64;
        #pragma unroll
        for (int j = 0; j < 4; j++)
          yrow[j * 16 + lr] = __float2bfloat16(ex[j] * inv);
      }
    }
  } else {
    // ---- fused context: tile = 256 s-rows x 2 heads (each head: 64 k | 64 v) ----
    const int bb2 = m0 >> 12;                 // batch (4096 rows per batch)
    const int h0 = (n0 - 1024) >> 7;          // first head of this tile
    const int hloc = wn >> 1, isV = wn & 1;   // wave role
    bf16* const dstT = (isV ? sm.c.vT[hloc] : sm.c.ekT[hloc]);

    float zp[4] = {0.f, 0.f, 0.f, 0.f};
    #pragma unroll
    for (int i = 0; i < 8; i++) {
      const int sbase = wm * 128 + i * 16 + kq * 4;
      const int sxo = sbase >> 3;             // chunk (constant across r)
      const int sby = (sbase & 7) * 2;        // byte offset within chunk (0 or 8)
      #pragma unroll
      for (int j = 0; j < 4; j++) {
        const int d = j * 16 + lr;
        B4 pk;
        if (!isV) {
          #pragma unroll
          for (int r = 0; r < 4; r++) {
            float e = __expf(acc[i][j][r]);
            zp[j] += e;
            pk.h[r] = __float2bfloat16(e);
          }
        } else {
          #pragma unroll
          for (int r = 0; r < 4; r++) pk.h[r] = __float2bfloat16(acc[i][j][r]);
        }
        *(B4*)((char*)dstT + d * 512 + ((sxo ^ (d & 7)) << 4) + sby) = pk;
      }
    }

    if (!isV) {
      // Z[d] partial over this wave's 128 s-rows, straight from registers
      #pragma unroll
      for (int j = 0; j < 4; j++) {
        zp[j] += __shfl_xor(zp[j], 16);
        zp[j] += __shfl_xor(zp[j], 32);
      }
      if (kq == 0) {
        float* zb = ctxAcc + (size_t)(bb2 * 16 + h0 + hloc) * 4160 + 4096;
        #pragma unroll
        for (int j = 0; j < 4; j++) atomicAdd(zb + j * 16 + lr, zp[j]);
      }
    }
    __syncthreads();

    // R[d][e] partial via MFMA over K=256 s-rows; wave -> (head = wave>>2, d-quad = wave&3)
    const int hh = wave >> 2, dq = wave & 3;
    const bf16* const ek = sm.c.ekT[hh];
    const bf16* const vv = sm.c.vT[hh];
    f32x4 racc[4] = {zero, zero, zero, zero};
    #pragma unroll
    for (int ks = 0; ks < 8; ks++) {
      const int ch = ks * 4 + kq;
      bf16x8 af = *(const bf16x8*)((const char*)ek + (dq * 16 + lr) * 512 + ((ch ^ (lr & 7)) << 4));
      #pragma unroll
      for (int j = 0; j < 4; j++) {
        bf16x8 bfr = *(const bf16x8*)((const char*)vv + (j * 16 + lr) * 512 + ((ch ^ (lr & 7)) << 4));
        racc[j] = __builtin_amdgcn_mfma_f32_16x16x32_bf16(af, bfr, racc[j], 0, 0, 0);
      }
    }
    float* cb = ctxAcc + (size_t)(bb2 * 16 + h0 + hh) * 4160;
    #pragma unroll
    for (int j = 0; j < 4; j++) {
      #pragma unroll
      for (int r = 0; r < 4; r++)
        atomicAdd(cb + (dq * 16 + kq * 4 + r) * 64 + j * 16 + lr, racc[j][r]);
    }
  }
}

// ---------------- W2T[b][n][h*64+d] = sum_e (R[bh][d][e]/Z[bh][d]) * WlinT[n][h*64+e]
// (ctx normalization folded in; reads fp32 ctxAcc directly)
__global__ __launch_bounds__(256) void make_w2t(const float* __restrict__ ctxAcc,
                                                const bf16* __restrict__ WlinT,
                                                bf16* __restrict__ W2T) {
  const int nc = blockIdx.x;      // 0..15
  const int bh = blockIdx.y;      // 0..127
  const int b = bh >> 4, h = bh & 15;
  const int t = threadIdx.x, lane = t & 63, w = t >> 6;
  const float* src = ctxAcc + (size_t)bh * 4160;
  const float invz = 1.0f / src[4096 + lane];   // Z[d], d = lane
  float creg[64];
  const float* crow = src + lane * 64;
  #pragma unroll
  for (int e4 = 0; e4 < 16; e4++) {
    float4 v = *(const float4*)(crow + e4 * 4);
    creg[e4 * 4 + 0] = v.x * invz; creg[e4 * 4 + 1] = v.y * invz;
    creg[e4 * 4 + 2] = v.z * invz; creg[e4 * 4 + 3] = v.w * invz;
  }
  for (int i = 0; i < 16; i++) {
    const int n = nc * 64 + w * 16 + i;
    const bf16* wrow = WlinT + (size_t)n * 1024 + h * 64;
    float acc = 0.f;
    #pragma unroll
    for (int e8 = 0; e8 < 8; e8++) {
      B8 v = *(const B8*)(wrow + e8 * 8);
      #pragma unroll
      for (int j = 0; j < 8; j++) acc += creg[e8 * 8 + j] * __bfloat162float(v.h[j]);
    }
    W2T[((size_t)b * 1024 + n) * 1024 + h * 64 + lane] = __float2bfloat16(acc);
  }
}

// ---------------- out[b] = Yq[b] @ W2T[b]^T + blin, fp32 output -------------------
// per batch: M=4096, N=1024, K=1024; 256x256 tiles, pipelined main loop; grid 512
// XCD-chunked swizzle: each XCD owns one batch (64 blocks): W2T[b] (2MB) L2-resident.
__global__ __launch_bounds__(512, 2)
void gemm_out(const bf16* __restrict__ Aall, const bf16* __restrict__ BTall,
              float* __restrict__ Call, const float* __restrict__ bias)
{
  __shared__ __align__(16) struct { bf16 a[4 * 8192]; bf16 b[4 * 8192]; } sm;
  const int t = threadIdx.x;
  const int wave = t >> 6, lane = t & 63;
  const int lr = lane & 15, kq = lane >> 4;
  const int wm = wave >> 2, wn = wave & 3;
  // bijective XCD swizzle: 512 = 8 * 64; XCD x -> batch x
  const int bid = (int)blockIdx.x;
  const int swz = (bid & 7) * 64 + (bid >> 3);
  const int bz = swz >> 6;
  const int r  = swz & 63;
  const int bm = r >> 2, bn = r & 3;
  const int m0 = bm * 256, n0 = bn * 256;
  const bf16* A  = Aall  + (size_t)bz * 4096 * 1024;
  const bf16* BT = BTall + (size_t)bz * 1024 * 1024;
  float* C       = Call  + (size_t)bz * 4096 * 1024;

  const int srow = t >> 2;
  const int cl = (t & 3) ^ ((srow ^ (srow >> 2)) & 3);
  const bf16* aop0 = A + (size_t)(m0 + srow) * 1024 + cl * 8;
  const bf16* aop1 = A + (size_t)(m0 + 128 + srow) * 1024 + cl * 8;
  const bf16* bop0 = BT + (size_t)(n0 + srow) * 1024 + cl * 8;
  const bf16* bop1 = BT + (size_t)(n0 + 128 + srow) * 1024 + cl * 8;
  const int wd0 = wave * 512;
  const int wd1 = 4096 + wave * 512;

  const int fc = (kq ^ ((lr ^ (lr >> 2)) & 3)) * 8;
  const int arow = wm * 128 + lr;
  const int brow = wn * 64 + lr;

  const f32x4 zero = {0.f, 0.f, 0.f, 0.f};
  f32x4 acc[8][4];
  #pragma unroll
  for (int i = 0; i < 8; i++)
    #pragma unroll
    for (int j = 0; j < 4; j++) acc[i][j] = zero;

  gemm_mainloop_256(aop0, aop1, bop0, bop1, sm.a, sm.b, wd0, wd1,
                    arow, brow, fc, acc);

  float bv[4];
  #pragma unroll
  for (int j = 0; j < 4; j++) bv[j] = bias[n0 + wn * 64 + j * 16 + lr];
  #pragma unroll
  for (int i = 0; i < 8; i++) {
    const int row0 = m0 + wm * 128 + i * 16 + kq * 4;
    #pragma unroll
    for (int j = 0; j < 4; j++) {
      const int col = n0 + wn * 64 + j * 16 + lr;
      const float bvj = bv[j];
      #pragma unroll
      for (int r2 = 0; r2 < 4; r2++)
        C[(size_t)(row0 + r2) * 1024 + col] = acc[i][j][r2] + bvj;
    }
  }
}

// ---------------------------------------------------------------------------------
extern "C" void kernel_launch(void* const* d_in, const int* in_sizes, int n_in,
                              void* d_out, int out_size, void* d_ws, size_t ws_size,
                              hipStream_t stream) {
  (void)in_sizes; (void)n_in; (void)out_size; (void)ws_size;
  const float* x    = (const float*)d_in[0];
  const float* Wq   = (const float*)d_in[1];
  const float* Wkv  = (const float*)d_in[2];
  const float* Wlin = (const float*)d_in[3];
  const float* blin = (const float*)d_in[4];
  float* out = (float*)d_out;              // reference output dtype = float32

  // workspace layout (~160 MB total)
  bf16* x_bf  = (bf16*)d_ws;                  // 33,554,432
  bf16* WTc   = x_bf + 33554432;              // 3,145,728   [Wq^T | Wkv^T]
  bf16* WlinT = WTc + 3145728;                // 1,048,576
  bf16* Yq    = WlinT + 1048576;              // 33,554,432  (q only)
  bf16* W2T   = Yq + 33554432;                // 8,388,608
  float* ctxAcc = (float*)(W2T + 8388608);    // 128 * 4160 fp32 (R | Z)

  cast_f32_bf16<<<16384, 256, 0, stream>>>(x, x_bf, 33554432LL);
  tcast<<<dim3(32, 32), dim3(32, 8), 0, stream>>>(Wq, WTc, 1024, 1024);
  tcast<<<dim3(64, 32), dim3(32, 8), 0, stream>>>(Wkv, WTc + 1048576, 1024, 2048);
  tcast<<<dim3(32, 32), dim3(32, 8), 0, stream>>>(Wlin, WlinT, 1024, 1024);

  hipMemsetAsync(ctxAcc, 0, (size_t)128 * 4160 * sizeof(float), stream);

  gemm_qkv<<<dim3(128 * QKV_NT), 512, 0, stream>>>(x_bf, WTc, Yq, ctxAcc);
  make_w2t<<<dim3(16, 128), 256, 0, stream>>>(ctxAcc, WlinT, W2T);
  gemm_out<<<dim3(512), 512, 0, stream>>>(Yq, W2T, out, blin);
}